// Round 1
// baseline (1863.802 us; speedup 1.0000x reference)
//
#include <hip/hip_runtime.h>
#include <math.h>

#define NN 50000
#define NE 800000
#define FF 768
#define HH 256

// ---------------- CSR build ----------------
__global__ void k_count(const int* __restrict__ dstv, int* __restrict__ deg) {
  int e = blockIdx.x * 256 + threadIdx.x;
  if (e < NE) atomicAdd(&deg[dstv[e]], 1);
}

__global__ void k_scan(const int* __restrict__ deg, int* __restrict__ rowptr) {
  __shared__ int buf[1024];
  __shared__ int carry;
  int tid = threadIdx.x;
  if (tid == 0) { carry = 0; rowptr[0] = 0; }
  __syncthreads();
  for (int base = 0; base < NN; base += 1024) {
    int i = base + tid;
    int v = (i < NN) ? deg[i] : 0;
    buf[tid] = v;
    __syncthreads();
    for (int off = 1; off < 1024; off <<= 1) {
      int t = (tid >= off) ? buf[tid - off] : 0;
      __syncthreads();
      buf[tid] += t;
      __syncthreads();
    }
    int incl = buf[tid] + carry;
    if (i < NN) rowptr[i + 1] = incl;
    __syncthreads();
    if (tid == 1023) carry = incl;
    __syncthreads();
  }
}

__global__ void k_scatter(const int* __restrict__ srcv, const int* __restrict__ dstv,
                          int* __restrict__ cursor, int* __restrict__ csr_src) {
  int e = blockIdx.x * 256 + threadIdx.x;
  if (e < NE) {
    int d = dstv[e];
    int pos = atomicAdd(&cursor[d], 1);
    csr_src[pos] = srcv[e];
  }
}

// ------------- aggregation: m = (1+eps)*h + sum_{src->n} h[src] -------------
// one wave (64 lanes) per node; lane l owns float4 chunk l of the 256-dim row
__global__ void k_agg(const float* __restrict__ h, const int* __restrict__ rowptr,
                      const int* __restrict__ csr_src, const float* __restrict__ eps,
                      int layer, float* __restrict__ m) {
  int node = (blockIdx.x * blockDim.x + threadIdx.x) >> 6;
  int lane = threadIdx.x & 63;
  if (node >= NN) return;
  int beg = rowptr[node], end = rowptr[node + 1];
  const float4* hv = (const float4*)h;
  float4 acc = make_float4(0.f, 0.f, 0.f, 0.f);
  for (int e = beg; e < end; ++e) {
    int s = csr_src[e];
    float4 v = hv[(size_t)s * 64 + lane];
    acc.x += v.x; acc.y += v.y; acc.z += v.z; acc.w += v.w;
  }
  float ep = 1.0f + eps[layer];
  float4 h0 = hv[(size_t)node * 64 + lane];
  acc.x += ep * h0.x; acc.y += ep * h0.y; acc.z += ep * h0.z; acc.w += ep * h0.w;
  ((float4*)m)[(size_t)node * 64 + lane] = acc;
}

// ---------------- tiled fp32 GEMM, BM=64, BN=256, BK=16 ----------------
// EPI 0: out = A@B + bias                      (input projection)
// EPI 1: out = relu(LN(A@B + bias; g,be))      (GIN mid, in-place A ok)
// EPI 2: out = relu(LN(A@B + bias; g,be)) + resid   (GIN out, resid=h)
template <int KTOT, int EPI>
__global__ __launch_bounds__(256) void k_gemm(
    const float* A, const float* __restrict__ B, const float* __restrict__ bias,
    const float* __restrict__ g, const float* __restrict__ be,
    const float* resid, float* out) {
  __shared__ float As[16][64];
  __shared__ float Bs[16][256];
  __shared__ float redS[64][17];
  __shared__ float redQ[64][17];
  __shared__ float mv[64][2];
  int tid = threadIdx.x;
  int tx = tid & 15, ty = tid >> 4;
  int row0 = blockIdx.x * 64;
  float acc[4][16];
#pragma unroll
  for (int i = 0; i < 4; i++)
#pragma unroll
    for (int j = 0; j < 16; j++) acc[i][j] = 0.f;
  int ar = tid >> 2;
  int ak = (tid & 3) * 4;
  int arow = row0 + ar; if (arow > NN - 1) arow = NN - 1;
  int bc4 = (tid & 63) * 4;
  int bk0 = tid >> 6;
  for (int k0 = 0; k0 < KTOT; k0 += 16) {
    float4 av = *(const float4*)&A[(size_t)arow * KTOT + k0 + ak];
    As[ak + 0][ar] = av.x; As[ak + 1][ar] = av.y;
    As[ak + 2][ar] = av.z; As[ak + 3][ar] = av.w;
#pragma unroll
    for (int it = 0; it < 4; it++) {
      int kk = bk0 + it * 4;
      *(float4*)&Bs[kk][bc4] = *(const float4*)&B[(size_t)(k0 + kk) * 256 + bc4];
    }
    __syncthreads();
#pragma unroll
    for (int k = 0; k < 16; k++) {
      float4 a4 = *(const float4*)&As[k][ty * 4];
      float avv[4] = {a4.x, a4.y, a4.z, a4.w};
      float4 b0 = *(const float4*)&Bs[k][tx * 16 + 0];
      float4 b1v = *(const float4*)&Bs[k][tx * 16 + 4];
      float4 b2v = *(const float4*)&Bs[k][tx * 16 + 8];
      float4 b3v = *(const float4*)&Bs[k][tx * 16 + 12];
      float bvv[16] = {b0.x, b0.y, b0.z, b0.w, b1v.x, b1v.y, b1v.z, b1v.w,
                       b2v.x, b2v.y, b2v.z, b2v.w, b3v.x, b3v.y, b3v.z, b3v.w};
#pragma unroll
      for (int i = 0; i < 4; i++)
#pragma unroll
        for (int j = 0; j < 16; j++) acc[i][j] = fmaf(avv[i], bvv[j], acc[i][j]);
    }
    __syncthreads();
  }
  if (EPI == 0) {
#pragma unroll
    for (int i = 0; i < 4; i++) {
      int r = row0 + ty * 4 + i;
      if (r < NN) {
#pragma unroll
        for (int q = 0; q < 4; q++) {
          int c = tx * 16 + q * 4;
          float4 o;
          o.x = acc[i][q * 4 + 0] + bias[c + 0];
          o.y = acc[i][q * 4 + 1] + bias[c + 1];
          o.z = acc[i][q * 4 + 2] + bias[c + 2];
          o.w = acc[i][q * 4 + 3] + bias[c + 3];
          *(float4*)&out[(size_t)r * 256 + c] = o;
        }
      }
    }
  } else {
#pragma unroll
    for (int i = 0; i < 4; i++) {
      float s = 0.f, q = 0.f;
#pragma unroll
      for (int j = 0; j < 16; j++) {
        float v = acc[i][j] + bias[tx * 16 + j];
        acc[i][j] = v;
        s += v; q += v * v;
      }
      redS[ty * 4 + i][tx] = s;
      redQ[ty * 4 + i][tx] = q;
    }
    __syncthreads();
    if (tid < 64) {
      float s = 0.f, q = 0.f;
#pragma unroll
      for (int t = 0; t < 16; t++) { s += redS[tid][t]; q += redQ[tid][t]; }
      float mean = s * (1.f / 256.f);
      float var = q * (1.f / 256.f) - mean * mean;
      mv[tid][0] = mean;
      mv[tid][1] = rsqrtf(var + 1e-5f);
    }
    __syncthreads();
#pragma unroll
    for (int i = 0; i < 4; i++) {
      int rr = ty * 4 + i;
      int r = row0 + rr;
      if (r < NN) {
        float mean = mv[rr][0], inv = mv[rr][1];
#pragma unroll
        for (int q2 = 0; q2 < 4; q2++) {
          int c = tx * 16 + q2 * 4;
          float o[4];
#pragma unroll
          for (int u = 0; u < 4; u++) {
            float val = (acc[i][q2 * 4 + u] - mean) * inv * g[c + u] + be[c + u];
            val = fmaxf(val, 0.f);
            if (EPI == 2) val += resid[(size_t)r * 256 + c + u];
            o[u] = val;
          }
          *(float4*)&out[(size_t)r * 256 + c] = make_float4(o[0], o[1], o[2], o[3]);
        }
      }
    }
  }
}

// ------------- attention: logitsT[k][n] = sum_a tanh(h@W1k + b1k)*W2k + b2k -------------
// BM=64, BN=128 (= one head per blockIdx.y), BK=16
__global__ __launch_bounds__(256) void k_att(const float* __restrict__ h,
    const float* __restrict__ W1, const float* __restrict__ b1,
    const float* __restrict__ W2, const float* __restrict__ b2,
    float* __restrict__ logitsT) {
  int kh = blockIdx.y;
  const float* B = W1 + (size_t)kh * 256 * 128;
  __shared__ float As[16][64];
  __shared__ float Bs[16][128];
  __shared__ float red[64][17];
  int tid = threadIdx.x;
  int tx = tid & 15, ty = tid >> 4;
  int row0 = blockIdx.x * 64;
  float acc[4][8];
#pragma unroll
  for (int i = 0; i < 4; i++)
#pragma unroll
    for (int j = 0; j < 8; j++) acc[i][j] = 0.f;
  int ar = tid >> 2;
  int ak = (tid & 3) * 4;
  int arow = row0 + ar; if (arow > NN - 1) arow = NN - 1;
  for (int k0 = 0; k0 < 256; k0 += 16) {
    float4 av = *(const float4*)&h[(size_t)arow * 256 + k0 + ak];
    As[ak + 0][ar] = av.x; As[ak + 1][ar] = av.y;
    As[ak + 2][ar] = av.z; As[ak + 3][ar] = av.w;
#pragma unroll
    for (int it = 0; it < 2; it++) {
      int idx = tid + it * 256;
      int kk = idx >> 5, c4 = (idx & 31) * 4;
      *(float4*)&Bs[kk][c4] = *(const float4*)&B[(size_t)(k0 + kk) * 128 + c4];
    }
    __syncthreads();
#pragma unroll
    for (int k = 0; k < 16; k++) {
      float4 a4 = *(const float4*)&As[k][ty * 4];
      float avv[4] = {a4.x, a4.y, a4.z, a4.w};
      float4 b0 = *(const float4*)&Bs[k][tx * 8];
      float4 b1v = *(const float4*)&Bs[k][tx * 8 + 4];
      float bvv[8] = {b0.x, b0.y, b0.z, b0.w, b1v.x, b1v.y, b1v.z, b1v.w};
#pragma unroll
      for (int i = 0; i < 4; i++)
#pragma unroll
        for (int j = 0; j < 8; j++) acc[i][j] = fmaf(avv[i], bvv[j], acc[i][j]);
    }
    __syncthreads();
  }
  const float* w2 = W2 + kh * 128;
  const float* bb1 = b1 + kh * 128;
#pragma unroll
  for (int i = 0; i < 4; i++) {
    float s = 0.f;
#pragma unroll
    for (int j = 0; j < 8; j++) {
      int c = tx * 8 + j;
      s += tanhf(acc[i][j] + bb1[c]) * w2[c];
    }
    red[ty * 4 + i][tx] = s;
  }
  __syncthreads();
  if (tid < 64) {
    float s = 0.f;
#pragma unroll
    for (int t = 0; t < 16; t++) s += red[tid][t];
    int r = row0 + tid;
    if (r < NN) logitsT[(size_t)kh * NN + r] = s + b2[kh];
  }
}

// ---------------- softmax over N per head ----------------
__global__ void k_smax1(const float* __restrict__ logitsT, float* __restrict__ pmax,
                        float* __restrict__ psum) {
  int k = blockIdx.y;
  int tid = threadIdx.x;
  const float* L = logitsT + (size_t)k * NN;
  __shared__ float sm[256];
  float mx = -1e30f;
  for (int i = blockIdx.x * 256 + tid; i < NN; i += 128 * 256) mx = fmaxf(mx, L[i]);
  sm[tid] = mx; __syncthreads();
  for (int o = 128; o >= 1; o >>= 1) { if (tid < o) sm[tid] = fmaxf(sm[tid], sm[tid + o]); __syncthreads(); }
  float bmax = sm[0];
  __syncthreads();
  float s = 0.f;
  for (int i = blockIdx.x * 256 + tid; i < NN; i += 128 * 256) s += __expf(L[i] - bmax);
  sm[tid] = s; __syncthreads();
  for (int o = 128; o >= 1; o >>= 1) { if (tid < o) sm[tid] += sm[tid + o]; __syncthreads(); }
  if (tid == 0) { pmax[k * 128 + blockIdx.x] = bmax; psum[k * 128 + blockIdx.x] = sm[0]; }
}

__global__ void k_smax2(const float* __restrict__ pmax, const float* __restrict__ psum,
                        float* __restrict__ gs) {
  int k = blockIdx.x;
  int tid = threadIdx.x;  // 128
  __shared__ float sm[128], sv[128];
  float m = pmax[k * 128 + tid];
  sm[tid] = m; __syncthreads();
  for (int o = 64; o >= 1; o >>= 1) { if (tid < o) sm[tid] = fmaxf(sm[tid], sm[tid + o]); __syncthreads(); }
  float gm = sm[0];
  __syncthreads();
  sv[tid] = psum[k * 128 + tid] * __expf(m - gm);
  __syncthreads();
  for (int o = 64; o >= 1; o >>= 1) { if (tid < o) sv[tid] += sv[tid + o]; __syncthreads(); }
  if (tid == 0) { gs[k * 2] = gm; gs[k * 2 + 1] = sv[0]; }
}

// ------------- a = softmax, attn output, z[k][d] partials -------------
__global__ void k_attnz(const float* __restrict__ logitsT, const float* __restrict__ gs,
                        const float* __restrict__ h, float* __restrict__ out_attn,
                        float* __restrict__ z) {
  int n0 = blockIdx.x * 128;
  int tid = threadIdx.x;
  __shared__ float a[4][128];
  for (int i = tid; i < 512; i += 256) {
    int k = i >> 7, n = i & 127;
    float v = 0.f;
    if (n0 + n < NN) v = __expf(logitsT[(size_t)k * NN + n0 + n] - gs[k * 2]) / gs[k * 2 + 1];
    a[k][n] = v;
  }
  __syncthreads();
  for (int i = tid; i < 512; i += 256) {
    int n = i >> 2, k = i & 3;
    if (n0 + n < NN) out_attn[(size_t)(n0 + n) * 4 + k] = a[k][n];
  }
  float z0 = 0.f, z1 = 0.f, z2 = 0.f, z3 = 0.f;
  int d = tid;  // 256 dims
  int nmax = NN - n0; if (nmax > 128) nmax = 128;
  for (int n = 0; n < nmax; n++) {
    float hv = h[(size_t)(n0 + n) * 256 + d];
    z0 += a[0][n] * hv; z1 += a[1][n] * hv; z2 += a[2][n] * hv; z3 += a[3][n] * hv;
  }
  atomicAdd(&z[0 * 256 + d], z0);
  atomicAdd(&z[1 * 256 + d], z1);
  atomicAdd(&z[2 * 256 + d], z2);
  atomicAdd(&z[3 * 256 + d], z3);
}

// ---------------- tiny classifier ----------------
__global__ void k_cls(const float* __restrict__ z, const float* __restrict__ Wc1,
                      const float* __restrict__ bc1, const float* __restrict__ g1,
                      const float* __restrict__ b1, const float* __restrict__ Wc2,
                      const float* __restrict__ bc2, const float* __restrict__ g2,
                      const float* __restrict__ b2, const float* __restrict__ Wc3,
                      const float* __restrict__ bc3, float* __restrict__ out) {
  int tid = threadIdx.x;  // 256
  __shared__ float za[256];
  __shared__ float buf[256];
  __shared__ float c1s[128];
  __shared__ float c2s[64];
  za[tid] = 0.25f * (z[tid] + z[256 + tid] + z[512 + tid] + z[768 + tid]);
  __syncthreads();
  float v1 = 0.f;
  if (tid < 128) {
    for (int d = 0; d < 256; d++) v1 += za[d] * Wc1[d * 128 + tid];
    v1 += bc1[tid];
  }
  buf[tid] = (tid < 128) ? v1 : 0.f; __syncthreads();
  for (int o = 128; o >= 1; o >>= 1) { if (tid < o) buf[tid] += buf[tid + o]; __syncthreads(); }
  float mean1 = buf[0] * (1.f / 128.f);
  __syncthreads();
  buf[tid] = (tid < 128) ? (v1 - mean1) * (v1 - mean1) : 0.f; __syncthreads();
  for (int o = 128; o >= 1; o >>= 1) { if (tid < o) buf[tid] += buf[tid + o]; __syncthreads(); }
  float inv1 = rsqrtf(buf[0] * (1.f / 128.f) + 1e-5f);
  __syncthreads();
  if (tid < 128) c1s[tid] = fmaxf((v1 - mean1) * inv1 * g1[tid] + b1[tid], 0.f);
  __syncthreads();
  float v2 = 0.f;
  if (tid < 64) {
    for (int d = 0; d < 128; d++) v2 += c1s[d] * Wc2[d * 64 + tid];
    v2 += bc2[tid];
  }
  buf[tid] = (tid < 64) ? v2 : 0.f; __syncthreads();
  for (int o = 128; o >= 1; o >>= 1) { if (tid < o) buf[tid] += buf[tid + o]; __syncthreads(); }
  float mean2 = buf[0] * (1.f / 64.f);
  __syncthreads();
  buf[tid] = (tid < 64) ? (v2 - mean2) * (v2 - mean2) : 0.f; __syncthreads();
  for (int o = 128; o >= 1; o >>= 1) { if (tid < o) buf[tid] += buf[tid + o]; __syncthreads(); }
  float inv2 = rsqrtf(buf[0] * (1.f / 64.f) + 1e-5f);
  __syncthreads();
  if (tid < 64) c2s[tid] = fmaxf((v2 - mean2) * inv2 * g2[tid] + b2[tid], 0.f);
  __syncthreads();
  if (tid < 7) {
    float l = 0.f;
    for (int d = 0; d < 64; d++) l += c2s[d] * Wc3[d * 7 + tid];
    buf[tid] = l + bc3[tid];
  }
  __syncthreads();
  if (tid == 0) {
    float mx = -1e30f;
    for (int i = 0; i < 7; i++) mx = fmaxf(mx, buf[i]);
    float s = 0.f;
    for (int i = 0; i < 7; i++) s += __expf(buf[i] - mx);
    for (int i = 0; i < 7; i++) out[i] = __expf(buf[i] - mx) / s;
  }
}

extern "C" void kernel_launch(void* const* d_in, const int* in_sizes, int n_in,
                              void* d_out, int out_size, void* d_ws, size_t ws_size,
                              hipStream_t stream) {
  const float* x       = (const float*)d_in[0];
  const int*   ei      = (const int*)d_in[1];
  const float* W_in    = (const float*)d_in[2];
  const float* b_in    = (const float*)d_in[3];
  const float* gin_W1  = (const float*)d_in[4];
  const float* gin_b1  = (const float*)d_in[5];
  const float* gin_lng = (const float*)d_in[6];
  const float* gin_lnb = (const float*)d_in[7];
  const float* gin_W2  = (const float*)d_in[8];
  const float* gin_b2  = (const float*)d_in[9];
  const float* eps     = (const float*)d_in[10];
  const float* ln_g    = (const float*)d_in[11];
  const float* ln_b    = (const float*)d_in[12];
  const float* att_W1  = (const float*)d_in[13];
  const float* att_b1  = (const float*)d_in[14];
  const float* att_W2  = (const float*)d_in[15];
  const float* att_b2  = (const float*)d_in[16];
  const float* Wc1     = (const float*)d_in[17];
  const float* bc1     = (const float*)d_in[18];
  const float* lnc1_g  = (const float*)d_in[19];
  const float* lnc1_b  = (const float*)d_in[20];
  const float* Wc2     = (const float*)d_in[21];
  const float* bc2     = (const float*)d_in[22];
  const float* lnc2_g  = (const float*)d_in[23];
  const float* lnc2_b  = (const float*)d_in[24];
  const float* Wc3     = (const float*)d_in[25];
  const float* bc3     = (const float*)d_in[26];
  float* out = (float*)d_out;
  (void)in_sizes; (void)n_in; (void)out_size; (void)ws_size;

  char* wsb = (char*)d_ws;
  size_t off = 0;
  auto alloc = [&](size_t bytes) {
    char* p = wsb + off;
    off += (bytes + 255) & ~(size_t)255;
    return p;
  };
  float* h       = (float*)alloc((size_t)NN * HH * 4);
  float* m       = (float*)alloc((size_t)NN * HH * 4);
  float* logitsT = (float*)alloc((size_t)4 * NN * 4);
  int*   deg     = (int*)alloc((size_t)NN * 4);
  int*   rowptr  = (int*)alloc((size_t)(NN + 1) * 4);
  int*   cursor  = (int*)alloc((size_t)NN * 4);
  int*   csr_src = (int*)alloc((size_t)NE * 4);
  float* pmax    = (float*)alloc(4 * 128 * 4);
  float* psum    = (float*)alloc(4 * 128 * 4);
  float* gs      = (float*)alloc(8 * 4);
  float* z       = (float*)alloc(4 * 256 * 4);

  const int* srcv = ei;
  const int* dstv = ei + NE;

  hipMemsetAsync(deg, 0, (size_t)NN * 4, stream);
  hipMemsetAsync(z, 0, 4 * 256 * 4, stream);
  k_count<<<(NE + 255) / 256, 256, 0, stream>>>(dstv, deg);
  k_scan<<<1, 1024, 0, stream>>>(deg, rowptr);
  hipMemcpyAsync(cursor, rowptr, (size_t)NN * 4, hipMemcpyDeviceToDevice, stream);
  k_scatter<<<(NE + 255) / 256, 256, 0, stream>>>(srcv, dstv, cursor, csr_src);

  int gblocks = (NN + 63) / 64;  // 782
  // h = x @ W_in + b_in
  k_gemm<FF, 0><<<gblocks, 256, 0, stream>>>(x, W_in, b_in, nullptr, nullptr, nullptr, h);

  for (int l = 0; l < 2; l++) {
    k_agg<<<(NN + 3) / 4, 256, 0, stream>>>(h, rowptr, csr_src, eps, l, m);
    // m = relu(LN(m @ W1 + b1))   (in-place: each block only reads/writes its own rows)
    k_gemm<HH, 1><<<gblocks, 256, 0, stream>>>(m, gin_W1 + (size_t)l * HH * HH, gin_b1 + l * HH,
                                               gin_lng + l * HH, gin_lnb + l * HH, nullptr, m);
    // h = relu(LN(m @ W2 + b2)) + h
    k_gemm<HH, 2><<<gblocks, 256, 0, stream>>>(m, gin_W2 + (size_t)l * HH * HH, gin_b2 + l * HH,
                                               ln_g + l * HH, ln_b + l * HH, h, h);
  }

  k_att<<<dim3(gblocks, 4), 256, 0, stream>>>(h, att_W1, att_b1, att_W2, att_b2, logitsT);
  k_smax1<<<dim3(128, 4), 256, 0, stream>>>(logitsT, pmax, psum);
  k_smax2<<<4, 128, 0, stream>>>(pmax, psum, gs);
  k_attnz<<<(NN + 127) / 128, 256, 0, stream>>>(logitsT, gs, h, out + 7, z);
  k_cls<<<1, 256, 0, stream>>>(z, Wc1, bc1, lnc1_g, lnc1_b, Wc2, bc2, lnc2_g, lnc2_b,
                               Wc3, bc3, out);
}

// Round 2
// 1837.000 us; speedup vs baseline: 1.0146x; 1.0146x over previous
//
#include <hip/hip_runtime.h>
#include <math.h>

#define NN 50000
#define NE 800000
#define FF 768
#define HH 256

// ---------------- CSR build ----------------
__global__ void k_count(const int* __restrict__ dstv, int* __restrict__ deg) {
  int e = blockIdx.x * 256 + threadIdx.x;
  if (e < NE) atomicAdd(&deg[dstv[e]], 1);
}

__global__ void k_scan(const int* __restrict__ deg, int* __restrict__ rowptr) {
  __shared__ int buf[1024];
  __shared__ int carry;
  int tid = threadIdx.x;
  if (tid == 0) { carry = 0; rowptr[0] = 0; }
  __syncthreads();
  for (int base = 0; base < NN; base += 1024) {
    int i = base + tid;
    int v = (i < NN) ? deg[i] : 0;
    buf[tid] = v;
    __syncthreads();
    for (int off = 1; off < 1024; off <<= 1) {
      int t = (tid >= off) ? buf[tid - off] : 0;
      __syncthreads();
      buf[tid] += t;
      __syncthreads();
    }
    int incl = buf[tid] + carry;
    if (i < NN) rowptr[i + 1] = incl;
    __syncthreads();
    if (tid == 1023) carry = incl;
    __syncthreads();
  }
}

__global__ void k_scatter(const int* __restrict__ srcv, const int* __restrict__ dstv,
                          int* __restrict__ cursor, int* __restrict__ csr_src) {
  int e = blockIdx.x * 256 + threadIdx.x;
  if (e < NE) {
    int d = dstv[e];
    int pos = atomicAdd(&cursor[d], 1);
    csr_src[pos] = srcv[e];
  }
}

// ------------- aggregation: m = (1+eps)*h + sum_{src->n} h[src] -------------
// one wave (64 lanes) per node; lane l owns float4 chunk l of the 256-dim row
__global__ void k_agg(const float* __restrict__ h, const int* __restrict__ rowptr,
                      const int* __restrict__ csr_src, const float* __restrict__ eps,
                      int layer, float* __restrict__ m) {
  int node = (blockIdx.x * blockDim.x + threadIdx.x) >> 6;
  int lane = threadIdx.x & 63;
  if (node >= NN) return;
  int beg = rowptr[node], end = rowptr[node + 1];
  const float4* hv = (const float4*)h;
  float4 acc = make_float4(0.f, 0.f, 0.f, 0.f);
  for (int e = beg; e < end; ++e) {
    int s = csr_src[e];
    float4 v = hv[(size_t)s * 64 + lane];
    acc.x += v.x; acc.y += v.y; acc.z += v.z; acc.w += v.w;
  }
  float ep = 1.0f + eps[layer];
  float4 h0 = hv[(size_t)node * 64 + lane];
  acc.x += ep * h0.x; acc.y += ep * h0.y; acc.z += ep * h0.z; acc.w += ep * h0.w;
  ((float4*)m)[(size_t)node * 64 + lane] = acc;
}

// ---------------- tiled fp32 GEMM, BM=64, BN=256, BK=16 ----------------
// EPI 0: out = A@B + bias                      (input projection)
// EPI 1: out = relu(LN(A@B + bias; g,be))      (GIN mid, in-place A ok)
// EPI 2: out = relu(LN(A@B + bias; g,be)) + resid   (GIN out, resid=h)
template <int KTOT, int EPI>
__global__ __launch_bounds__(256) void k_gemm(
    const float* A, const float* __restrict__ B, const float* __restrict__ bias,
    const float* __restrict__ g, const float* __restrict__ be,
    const float* resid, float* out) {
  __shared__ float As[16][64];
  __shared__ float Bs[16][256];
  __shared__ float redS[64][17];
  __shared__ float redQ[64][17];
  __shared__ float mv[64][2];
  int tid = threadIdx.x;
  int tx = tid & 15, ty = tid >> 4;
  int row0 = blockIdx.x * 64;
  float acc[4][16];
#pragma unroll
  for (int i = 0; i < 4; i++)
#pragma unroll
    for (int j = 0; j < 16; j++) acc[i][j] = 0.f;
  int ar = tid >> 2;
  int ak = (tid & 3) * 4;
  int arow = row0 + ar; if (arow > NN - 1) arow = NN - 1;
  int bc4 = (tid & 63) * 4;
  int bk0 = tid >> 6;
  for (int k0 = 0; k0 < KTOT; k0 += 16) {
    float4 av = *(const float4*)&A[(size_t)arow * KTOT + k0 + ak];
    As[ak + 0][ar] = av.x; As[ak + 1][ar] = av.y;
    As[ak + 2][ar] = av.z; As[ak + 3][ar] = av.w;
#pragma unroll
    for (int it = 0; it < 4; it++) {
      int kk = bk0 + it * 4;
      *(float4*)&Bs[kk][bc4] = *(const float4*)&B[(size_t)(k0 + kk) * 256 + bc4];
    }
    __syncthreads();
#pragma unroll
    for (int k = 0; k < 16; k++) {
      float4 a4 = *(const float4*)&As[k][ty * 4];
      float avv[4] = {a4.x, a4.y, a4.z, a4.w};
      float4 b0 = *(const float4*)&Bs[k][tx * 16 + 0];
      float4 b1v = *(const float4*)&Bs[k][tx * 16 + 4];
      float4 b2v = *(const float4*)&Bs[k][tx * 16 + 8];
      float4 b3v = *(const float4*)&Bs[k][tx * 16 + 12];
      float bvv[16] = {b0.x, b0.y, b0.z, b0.w, b1v.x, b1v.y, b1v.z, b1v.w,
                       b2v.x, b2v.y, b2v.z, b2v.w, b3v.x, b3v.y, b3v.z, b3v.w};
#pragma unroll
      for (int i = 0; i < 4; i++)
#pragma unroll
        for (int j = 0; j < 16; j++) acc[i][j] = fmaf(avv[i], bvv[j], acc[i][j]);
    }
    __syncthreads();
  }
  if (EPI == 0) {
#pragma unroll
    for (int i = 0; i < 4; i++) {
      int r = row0 + ty * 4 + i;
      if (r < NN) {
#pragma unroll
        for (int q = 0; q < 4; q++) {
          int c = tx * 16 + q * 4;
          float4 o;
          o.x = acc[i][q * 4 + 0] + bias[c + 0];
          o.y = acc[i][q * 4 + 1] + bias[c + 1];
          o.z = acc[i][q * 4 + 2] + bias[c + 2];
          o.w = acc[i][q * 4 + 3] + bias[c + 3];
          *(float4*)&out[(size_t)r * 256 + c] = o;
        }
      }
    }
  } else {
#pragma unroll
    for (int i = 0; i < 4; i++) {
      float s = 0.f, q = 0.f;
#pragma unroll
      for (int j = 0; j < 16; j++) {
        float v = acc[i][j] + bias[tx * 16 + j];
        acc[i][j] = v;
        s += v; q += v * v;
      }
      redS[ty * 4 + i][tx] = s;
      redQ[ty * 4 + i][tx] = q;
    }
    __syncthreads();
    if (tid < 64) {
      float s = 0.f, q = 0.f;
#pragma unroll
      for (int t = 0; t < 16; t++) { s += redS[tid][t]; q += redQ[tid][t]; }
      float mean = s * (1.f / 256.f);
      float var = q * (1.f / 256.f) - mean * mean;
      mv[tid][0] = mean;
      mv[tid][1] = rsqrtf(var + 1e-5f);
    }
    __syncthreads();
#pragma unroll
    for (int i = 0; i < 4; i++) {
      int rr = ty * 4 + i;
      int r = row0 + rr;
      if (r < NN) {
        float mean = mv[rr][0], inv = mv[rr][1];
#pragma unroll
        for (int q2 = 0; q2 < 4; q2++) {
          int c = tx * 16 + q2 * 4;
          float o[4];
#pragma unroll
          for (int u = 0; u < 4; u++) {
            float val = (acc[i][q2 * 4 + u] - mean) * inv * g[c + u] + be[c + u];
            val = fmaxf(val, 0.f);
            if (EPI == 2) val += resid[(size_t)r * 256 + c + u];
            o[u] = val;
          }
          *(float4*)&out[(size_t)r * 256 + c] = make_float4(o[0], o[1], o[2], o[3]);
        }
      }
    }
  }
}

// ------------- attention: logitsT[k][n] = sum_a tanh(h@W1k + b1k)*W2k + b2k -------------
// BM=64, BN=128 (= one head per blockIdx.y), BK=16
__global__ __launch_bounds__(256) void k_att(const float* __restrict__ h,
    const float* __restrict__ W1, const float* __restrict__ b1,
    const float* __restrict__ W2, const float* __restrict__ b2,
    float* __restrict__ logitsT) {
  int kh = blockIdx.y;
  const float* B = W1 + (size_t)kh * 256 * 128;
  __shared__ float As[16][64];
  __shared__ float Bs[16][128];
  __shared__ float red[64][17];
  int tid = threadIdx.x;
  int tx = tid & 15, ty = tid >> 4;
  int row0 = blockIdx.x * 64;
  float acc[4][8];
#pragma unroll
  for (int i = 0; i < 4; i++)
#pragma unroll
    for (int j = 0; j < 8; j++) acc[i][j] = 0.f;
  int ar = tid >> 2;
  int ak = (tid & 3) * 4;
  int arow = row0 + ar; if (arow > NN - 1) arow = NN - 1;
  for (int k0 = 0; k0 < 256; k0 += 16) {
    float4 av = *(const float4*)&h[(size_t)arow * 256 + k0 + ak];
    As[ak + 0][ar] = av.x; As[ak + 1][ar] = av.y;
    As[ak + 2][ar] = av.z; As[ak + 3][ar] = av.w;
#pragma unroll
    for (int it = 0; it < 2; it++) {
      int idx = tid + it * 256;
      int kk = idx >> 5, c4 = (idx & 31) * 4;
      *(float4*)&Bs[kk][c4] = *(const float4*)&B[(size_t)(k0 + kk) * 128 + c4];
    }
    __syncthreads();
#pragma unroll
    for (int k = 0; k < 16; k++) {
      float4 a4 = *(const float4*)&As[k][ty * 4];
      float avv[4] = {a4.x, a4.y, a4.z, a4.w};
      float4 b0 = *(const float4*)&Bs[k][tx * 8];
      float4 b1v = *(const float4*)&Bs[k][tx * 8 + 4];
      float bvv[8] = {b0.x, b0.y, b0.z, b0.w, b1v.x, b1v.y, b1v.z, b1v.w};
#pragma unroll
      for (int i = 0; i < 4; i++)
#pragma unroll
        for (int j = 0; j < 8; j++) acc[i][j] = fmaf(avv[i], bvv[j], acc[i][j]);
    }
    __syncthreads();
  }
  const float* w2 = W2 + kh * 128;
  const float* bb1 = b1 + kh * 128;
#pragma unroll
  for (int i = 0; i < 4; i++) {
    float s = 0.f;
#pragma unroll
    for (int j = 0; j < 8; j++) {
      int c = tx * 8 + j;
      s += tanhf(acc[i][j] + bb1[c]) * w2[c];
    }
    red[ty * 4 + i][tx] = s;
  }
  __syncthreads();
  if (tid < 64) {
    float s = 0.f;
#pragma unroll
    for (int t = 0; t < 16; t++) s += red[tid][t];
    int r = row0 + tid;
    if (r < NN) logitsT[(size_t)kh * NN + r] = s + b2[kh];
  }
}

// ---------------- softmax over N per head ----------------
__global__ void k_smax1(const float* __restrict__ logitsT, float* __restrict__ pmax,
                        float* __restrict__ psum) {
  int k = blockIdx.y;
  int tid = threadIdx.x;
  const float* L = logitsT + (size_t)k * NN;
  __shared__ float sm[256];
  float mx = -1e30f;
  for (int i = blockIdx.x * 256 + tid; i < NN; i += 128 * 256) mx = fmaxf(mx, L[i]);
  sm[tid] = mx; __syncthreads();
  for (int o = 128; o >= 1; o >>= 1) { if (tid < o) sm[tid] = fmaxf(sm[tid], sm[tid + o]); __syncthreads(); }
  float bmax = sm[0];
  __syncthreads();
  float s = 0.f;
  for (int i = blockIdx.x * 256 + tid; i < NN; i += 128 * 256) s += __expf(L[i] - bmax);
  sm[tid] = s; __syncthreads();
  for (int o = 128; o >= 1; o >>= 1) { if (tid < o) sm[tid] += sm[tid + o]; __syncthreads(); }
  if (tid == 0) { pmax[k * 128 + blockIdx.x] = bmax; psum[k * 128 + blockIdx.x] = sm[0]; }
}

__global__ void k_smax2(const float* __restrict__ pmax, const float* __restrict__ psum,
                        float* __restrict__ gs) {
  int k = blockIdx.x;
  int tid = threadIdx.x;  // 128
  __shared__ float sm[128], sv[128];
  float m = pmax[k * 128 + tid];
  sm[tid] = m; __syncthreads();
  for (int o = 64; o >= 1; o >>= 1) { if (tid < o) sm[tid] = fmaxf(sm[tid], sm[tid + o]); __syncthreads(); }
  float gm = sm[0];
  __syncthreads();
  sv[tid] = psum[k * 128 + tid] * __expf(m - gm);
  __syncthreads();
  for (int o = 64; o >= 1; o >>= 1) { if (tid < o) sv[tid] += sv[tid + o]; __syncthreads(); }
  if (tid == 0) { gs[k * 2] = gm; gs[k * 2 + 1] = sv[0]; }
}

// ------------- a = softmax, attn output, z[k][d] partials -------------
__global__ void k_attnz(const float* __restrict__ logitsT, const float* __restrict__ gs,
                        const float* __restrict__ h, float* __restrict__ out_attn,
                        float* __restrict__ z) {
  int n0 = blockIdx.x * 128;
  int tid = threadIdx.x;
  __shared__ float a[4][128];
  for (int i = tid; i < 512; i += 256) {
    int k = i >> 7, n = i & 127;
    float v = 0.f;
    if (n0 + n < NN) v = __expf(logitsT[(size_t)k * NN + n0 + n] - gs[k * 2]) / gs[k * 2 + 1];
    a[k][n] = v;
  }
  __syncthreads();
  for (int i = tid; i < 512; i += 256) {
    int n = i >> 2, k = i & 3;
    if (n0 + n < NN) out_attn[(size_t)(n0 + n) * 4 + k] = a[k][n];
  }
  float z0 = 0.f, z1 = 0.f, z2 = 0.f, z3 = 0.f;
  int d = tid;  // 256 dims
  int nmax = NN - n0; if (nmax > 128) nmax = 128;
  for (int n = 0; n < nmax; n++) {
    float hv = h[(size_t)(n0 + n) * 256 + d];
    z0 += a[0][n] * hv; z1 += a[1][n] * hv; z2 += a[2][n] * hv; z3 += a[3][n] * hv;
  }
  atomicAdd(&z[0 * 256 + d], z0);
  atomicAdd(&z[1 * 256 + d], z1);
  atomicAdd(&z[2 * 256 + d], z2);
  atomicAdd(&z[3 * 256 + d], z3);
}

// ---------------- tiny classifier ----------------
__global__ void k_cls(const float* __restrict__ z, const float* __restrict__ Wc1,
                      const float* __restrict__ bc1, const float* __restrict__ g1,
                      const float* __restrict__ b1, const float* __restrict__ Wc2,
                      const float* __restrict__ bc2, const float* __restrict__ g2,
                      const float* __restrict__ b2, const float* __restrict__ Wc3,
                      const float* __restrict__ bc3, float* __restrict__ out) {
  int tid = threadIdx.x;  // 256
  __shared__ float za[256];
  __shared__ float buf[256];
  __shared__ float c1s[128];
  __shared__ float c2s[64];
  za[tid] = 0.25f * (z[tid] + z[256 + tid] + z[512 + tid] + z[768 + tid]);
  __syncthreads();
  float v1 = 0.f;
  if (tid < 128) {
    for (int d = 0; d < 256; d++) v1 += za[d] * Wc1[d * 128 + tid];
    v1 += bc1[tid];
  }
  buf[tid] = (tid < 128) ? v1 : 0.f; __syncthreads();
  for (int o = 128; o >= 1; o >>= 1) { if (tid < o) buf[tid] += buf[tid + o]; __syncthreads(); }
  float mean1 = buf[0] * (1.f / 128.f);
  __syncthreads();
  buf[tid] = (tid < 128) ? (v1 - mean1) * (v1 - mean1) : 0.f; __syncthreads();
  for (int o = 128; o >= 1; o >>= 1) { if (tid < o) buf[tid] += buf[tid + o]; __syncthreads(); }
  float inv1 = rsqrtf(buf[0] * (1.f / 128.f) + 1e-5f);
  __syncthreads();
  if (tid < 128) c1s[tid] = fmaxf((v1 - mean1) * inv1 * g1[tid] + b1[tid], 0.f);
  __syncthreads();
  float v2 = 0.f;
  if (tid < 64) {
    for (int d = 0; d < 128; d++) v2 += c1s[d] * Wc2[d * 64 + tid];
    v2 += bc2[tid];
  }
  buf[tid] = (tid < 64) ? v2 : 0.f; __syncthreads();
  for (int o = 128; o >= 1; o >>= 1) { if (tid < o) buf[tid] += buf[tid + o]; __syncthreads(); }
  float mean2 = buf[0] * (1.f / 64.f);
  __syncthreads();
  buf[tid] = (tid < 64) ? (v2 - mean2) * (v2 - mean2) : 0.f; __syncthreads();
  for (int o = 128; o >= 1; o >>= 1) { if (tid < o) buf[tid] += buf[tid + o]; __syncthreads(); }
  float inv2 = rsqrtf(buf[0] * (1.f / 64.f) + 1e-5f);
  __syncthreads();
  if (tid < 64) c2s[tid] = fmaxf((v2 - mean2) * inv2 * g2[tid] + b2[tid], 0.f);
  __syncthreads();
  if (tid < 7) {
    float l = 0.f;
    for (int d = 0; d < 64; d++) l += c2s[d] * Wc3[d * 7 + tid];
    buf[tid] = l + bc3[tid];
  }
  __syncthreads();
  if (tid == 0) {
    float mx = -1e30f;
    for (int i = 0; i < 7; i++) mx = fmaxf(mx, buf[i]);
    float s = 0.f;
    for (int i = 0; i < 7; i++) s += __expf(buf[i] - mx);
    for (int i = 0; i < 7; i++) out[i] = __expf(buf[i] - mx) / s;
  }
}

extern "C" void kernel_launch(void* const* d_in, const int* in_sizes, int n_in,
                              void* d_out, int out_size, void* d_ws, size_t ws_size,
                              hipStream_t stream) {
  const float* x       = (const float*)d_in[0];
  const int*   ei      = (const int*)d_in[1];
  const float* W_in    = (const float*)d_in[2];
  const float* b_in    = (const float*)d_in[3];
  const float* gin_W1  = (const float*)d_in[4];
  const float* gin_b1  = (const float*)d_in[5];
  const float* gin_lng = (const float*)d_in[6];
  const float* gin_lnb = (const float*)d_in[7];
  const float* gin_W2  = (const float*)d_in[8];
  const float* gin_b2  = (const float*)d_in[9];
  const float* eps     = (const float*)d_in[10];
  const float* ln_g    = (const float*)d_in[11];
  const float* ln_b    = (const float*)d_in[12];
  const float* att_W1  = (const float*)d_in[13];
  const float* att_b1  = (const float*)d_in[14];
  const float* att_W2  = (const float*)d_in[15];
  const float* att_b2  = (const float*)d_in[16];
  const float* Wc1     = (const float*)d_in[17];
  const float* bc1     = (const float*)d_in[18];
  const float* lnc1_g  = (const float*)d_in[19];
  const float* lnc1_b  = (const float*)d_in[20];
  const float* Wc2     = (const float*)d_in[21];
  const float* bc2     = (const float*)d_in[22];
  const float* lnc2_g  = (const float*)d_in[23];
  const float* lnc2_b  = (const float*)d_in[24];
  const float* Wc3     = (const float*)d_in[25];
  const float* bc3     = (const float*)d_in[26];
  float* out = (float*)d_out;
  (void)in_sizes; (void)n_in; (void)out_size; (void)ws_size;

  char* wsb = (char*)d_ws;
  size_t off = 0;
  auto alloc = [&](size_t bytes) {
    char* p = wsb + off;
    off += (bytes + 255) & ~(size_t)255;
    return p;
  };
  float* h       = (float*)alloc((size_t)NN * HH * 4);
  float* m       = (float*)alloc((size_t)NN * HH * 4);
  float* logitsT = (float*)alloc((size_t)4 * NN * 4);
  int*   deg     = (int*)alloc((size_t)NN * 4);
  int*   rowptr  = (int*)alloc((size_t)(NN + 1) * 4);
  int*   cursor  = (int*)alloc((size_t)NN * 4);
  int*   csr_src = (int*)alloc((size_t)NE * 4);
  float* pmax    = (float*)alloc(4 * 128 * 4);
  float* psum    = (float*)alloc(4 * 128 * 4);
  float* gs      = (float*)alloc(8 * 4);
  float* z       = (float*)alloc(4 * 256 * 4);

  const int* srcv = ei;
  const int* dstv = ei + NE;

  hipMemsetAsync(deg, 0, (size_t)NN * 4, stream);
  hipMemsetAsync(z, 0, 4 * 256 * 4, stream);
  k_count<<<(NE + 255) / 256, 256, 0, stream>>>(dstv, deg);
  k_scan<<<1, 1024, 0, stream>>>(deg, rowptr);
  hipMemcpyAsync(cursor, rowptr, (size_t)NN * 4, hipMemcpyDeviceToDevice, stream);
  k_scatter<<<(NE + 255) / 256, 256, 0, stream>>>(srcv, dstv, cursor, csr_src);

  int gblocks = (NN + 63) / 64;  // 782
  // h = x @ W_in + b_in
  k_gemm<FF, 0><<<gblocks, 256, 0, stream>>>(x, W_in, b_in, nullptr, nullptr, nullptr, h);

  for (int l = 0; l < 2; l++) {
    k_agg<<<(NN + 3) / 4, 256, 0, stream>>>(h, rowptr, csr_src, eps, l, m);
    // m = relu(LN(m @ W1 + b1))   (in-place: each block only reads/writes its own rows)
    k_gemm<HH, 1><<<gblocks, 256, 0, stream>>>(m, gin_W1 + (size_t)l * HH * HH, gin_b1 + l * HH,
                                               gin_lng + l * HH, gin_lnb + l * HH, nullptr, m);
    // h = relu(LN(m @ W2 + b2)) + h
    k_gemm<HH, 2><<<gblocks, 256, 0, stream>>>(m, gin_W2 + (size_t)l * HH * HH, gin_b2 + l * HH,
                                               ln_g + l * HH, ln_b + l * HH, h, h);
  }

  k_att<<<dim3(gblocks, 4), 256, 0, stream>>>(h, att_W1, att_b1, att_W2, att_b2, logitsT);
  k_smax1<<<dim3(128, 4), 256, 0, stream>>>(logitsT, pmax, psum);
  k_smax2<<<4, 128, 0, stream>>>(pmax, psum, gs);
  k_attnz<<<(NN + 127) / 128, 256, 0, stream>>>(logitsT, gs, h, out + 7, z);
  k_cls<<<1, 256, 0, stream>>>(z, Wc1, bc1, lnc1_g, lnc1_b, Wc2, bc2, lnc2_g, lnc2_b,
                               Wc3, bc3, out);
}

// Round 3
// 977.565 us; speedup vs baseline: 1.9066x; 1.8792x over previous
//
#include <hip/hip_runtime.h>
#include <math.h>

#define NN 50000
#define NE 800000
#define FF 768
#define HH 256

typedef __attribute__((ext_vector_type(8))) short short8;
typedef __attribute__((ext_vector_type(4))) float f32x4;

__device__ inline unsigned short f2bf(float f) {
  unsigned u = __float_as_uint(f);
  u = u + 0x7fffu + ((u >> 16) & 1u);
  return (unsigned short)(u >> 16);
}

// ---------------- CSR build ----------------
__global__ void k_count(const int* __restrict__ dstv, int* __restrict__ deg) {
  int e = blockIdx.x * 256 + threadIdx.x;
  if (e < NE) atomicAdd(&deg[dstv[e]], 1);
}

__global__ void k_scan(const int* __restrict__ deg, int* __restrict__ rowptr) {
  __shared__ int buf[1024];
  __shared__ int carry;
  int tid = threadIdx.x;
  if (tid == 0) { carry = 0; rowptr[0] = 0; }
  __syncthreads();
  for (int base = 0; base < NN; base += 1024) {
    int i = base + tid;
    int v = (i < NN) ? deg[i] : 0;
    buf[tid] = v;
    __syncthreads();
    for (int off = 1; off < 1024; off <<= 1) {
      int t = (tid >= off) ? buf[tid - off] : 0;
      __syncthreads();
      buf[tid] += t;
      __syncthreads();
    }
    int incl = buf[tid] + carry;
    if (i < NN) rowptr[i + 1] = incl;
    __syncthreads();
    if (tid == 1023) carry = incl;
    __syncthreads();
  }
}

__global__ void k_scatter(const int* __restrict__ srcv, const int* __restrict__ dstv,
                          int* __restrict__ cursor, int* __restrict__ csr_src) {
  int e = blockIdx.x * 256 + threadIdx.x;
  if (e < NE) {
    int d = dstv[e];
    int pos = atomicAdd(&cursor[d], 1);
    csr_src[pos] = srcv[e];
  }
}

// ------------- aggregation: mb = bf16((1+eps)*h + sum_{src->n} h[src]) -------------
__global__ void k_agg(const float* __restrict__ h, const int* __restrict__ rowptr,
                      const int* __restrict__ csr_src, const float* __restrict__ eps,
                      int layer, unsigned short* __restrict__ mb) {
  int node = (blockIdx.x * blockDim.x + threadIdx.x) >> 6;
  int lane = threadIdx.x & 63;
  if (node >= NN) return;
  int beg = rowptr[node], end = rowptr[node + 1];
  const float4* hv = (const float4*)h;
  float4 acc = make_float4(0.f, 0.f, 0.f, 0.f);
  for (int e = beg; e < end; ++e) {
    int s = csr_src[e];
    float4 v = hv[(size_t)s * 64 + lane];
    acc.x += v.x; acc.y += v.y; acc.z += v.z; acc.w += v.w;
  }
  float ep = 1.0f + eps[layer];
  float4 h0 = hv[(size_t)node * 64 + lane];
  acc.x += ep * h0.x; acc.y += ep * h0.y; acc.z += ep * h0.z; acc.w += ep * h0.w;
  ushort4 o;
  o.x = f2bf(acc.x); o.y = f2bf(acc.y); o.z = f2bf(acc.z); o.w = f2bf(acc.w);
  *(ushort4*)&mb[(size_t)node * 256 + lane * 4] = o;
}

// ------------- transpose + cast: dst[c][r] = bf16(src[r][c]), src is R x C -------------
__global__ void k_tcast(const float* __restrict__ src, unsigned short* __restrict__ dst,
                        int R, int C) {
  __shared__ float tile[32][33];
  int bx = blockIdx.x * 32, by = blockIdx.y * 32;
  int tx = threadIdx.x & 31, ty = threadIdx.x >> 5;  // 32 x 8
  for (int i = 0; i < 32; i += 8) {
    int r = by + ty + i, c = bx + tx;
    tile[ty + i][tx] = (r < R && c < C) ? src[(size_t)r * C + c] : 0.f;
  }
  __syncthreads();
  for (int i = 0; i < 32; i += 8) {
    int c = bx + ty + i, r = by + tx;
    if (c < C && r < R) dst[(size_t)c * R + r] = f2bf(tile[tx][ty + i]);
  }
}

// ---------------- bf16 MFMA GEMM: block tile 64 x 256, BK=32 ----------------
// 4 waves; wave w computes rows 0..63 x cols [64w, 64w+64) as 4x4 tiles of 16x16x32.
// A: row-major [M][KTOT] (fp32 if AF32, else bf16-as-ushort). Bt: [256][KTOT] bf16 (B^T).
// EPI 0: outf = A@B + bias                              (fp32)
// EPI 1: outb = bf16(relu(LN(A@B + bias; g,be)))
// EPI 2: v = relu(LN(A@B+bias; g,be)) + resid; outf = v (fp32); outb = bf16(v)
template <int KTOT, int EPI, bool AF32>
__global__ __launch_bounds__(256) void k_mm(
    const void* __restrict__ Ap, const unsigned short* __restrict__ Bt,
    const float* __restrict__ bias, const float* __restrict__ g,
    const float* __restrict__ be, const float* __restrict__ resid,
    float* __restrict__ outf, unsigned short* __restrict__ outb) {
  __shared__ unsigned short As[64 * 40];   // 64 rows x 32 k, padded to 40
  __shared__ unsigned short Bs[256 * 40];  // 256 n-rows x 32 k, padded to 40
  __shared__ float redS[4][64];
  __shared__ float redQ[4][64];
  __shared__ float mvM[64], mvI[64];
  int t = threadIdx.x, lane = t & 63, wave = t >> 6;
  int row0 = blockIdx.x * 64;
  f32x4 acc[4][4];
#pragma unroll
  for (int i = 0; i < 4; i++)
#pragma unroll
    for (int j = 0; j < 4; j++) acc[i][j] = (f32x4)(0.f);
  int arow = t >> 2, ac = t & 3;
  int agr = row0 + arow; if (agr >= NN) agr = NN - 1;
  int m16 = lane & 15, kq = lane >> 4;

  for (int k0 = 0; k0 < KTOT; k0 += 32) {
    if (AF32) {
      const float* Af = (const float*)Ap + (size_t)agr * KTOT + k0 + ac * 8;
      float4 f0 = *(const float4*)Af;
      float4 f1 = *(const float4*)(Af + 4);
      short8 v;
      v[0] = (short)f2bf(f0.x); v[1] = (short)f2bf(f0.y);
      v[2] = (short)f2bf(f0.z); v[3] = (short)f2bf(f0.w);
      v[4] = (short)f2bf(f1.x); v[5] = (short)f2bf(f1.y);
      v[6] = (short)f2bf(f1.z); v[7] = (short)f2bf(f1.w);
      *(short8*)&As[arow * 40 + ac * 8] = v;
    } else {
      const unsigned short* Ab = (const unsigned short*)Ap + (size_t)agr * KTOT + k0 + ac * 8;
      *(float4*)&As[arow * 40 + ac * 8] = *(const float4*)Ab;
    }
#pragma unroll
    for (int it = 0; it < 4; it++) {
      int idx = t + it * 256;
      int br = idx >> 2, bc = idx & 3;
      *(float4*)&Bs[br * 40 + bc * 8] = *(const float4*)&Bt[(size_t)br * KTOT + k0 + bc * 8];
    }
    __syncthreads();
    short8 a[4], b[4];
#pragma unroll
    for (int rt = 0; rt < 4; rt++) a[rt] = *(const short8*)&As[(rt * 16 + m16) * 40 + kq * 8];
#pragma unroll
    for (int ct = 0; ct < 4; ct++)
      b[ct] = *(const short8*)&Bs[(wave * 64 + ct * 16 + m16) * 40 + kq * 8];
#pragma unroll
    for (int rt = 0; rt < 4; rt++)
#pragma unroll
      for (int ct = 0; ct < 4; ct++)
        acc[rt][ct] = __builtin_amdgcn_mfma_f32_16x16x32_bf16(a[rt], b[ct], acc[rt][ct], 0, 0, 0);
    __syncthreads();
  }

  int colbase = wave * 64 + m16;
  float bv[4];
#pragma unroll
  for (int ct = 0; ct < 4; ct++) bv[ct] = bias[colbase + ct * 16];

  if (EPI == 0) {
#pragma unroll
    for (int rt = 0; rt < 4; rt++)
#pragma unroll
      for (int reg = 0; reg < 4; reg++) {
        int r = row0 + rt * 16 + kq * 4 + reg;
        if (r < NN) {
#pragma unroll
          for (int ct = 0; ct < 4; ct++)
            outf[(size_t)r * 256 + colbase + ct * 16] = acc[rt][ct][reg] + bv[ct];
        }
      }
    return;
  }

  float s[4][4], q[4][4];
#pragma unroll
  for (int rt = 0; rt < 4; rt++)
#pragma unroll
    for (int reg = 0; reg < 4; reg++) { s[rt][reg] = 0.f; q[rt][reg] = 0.f; }
#pragma unroll
  for (int rt = 0; rt < 4; rt++)
#pragma unroll
    for (int ct = 0; ct < 4; ct++)
#pragma unroll
      for (int reg = 0; reg < 4; reg++) {
        float v = acc[rt][ct][reg] + bv[ct];
        acc[rt][ct][reg] = v;
        s[rt][reg] += v;
        q[rt][reg] += v * v;
      }
#pragma unroll
  for (int off = 1; off < 16; off <<= 1) {
#pragma unroll
    for (int rt = 0; rt < 4; rt++)
#pragma unroll
      for (int reg = 0; reg < 4; reg++) {
        s[rt][reg] += __shfl_xor(s[rt][reg], off, 64);
        q[rt][reg] += __shfl_xor(q[rt][reg], off, 64);
      }
  }
  if (m16 == 0) {
#pragma unroll
    for (int rt = 0; rt < 4; rt++)
#pragma unroll
      for (int reg = 0; reg < 4; reg++) {
        redS[wave][rt * 16 + kq * 4 + reg] = s[rt][reg];
        redQ[wave][rt * 16 + kq * 4 + reg] = q[rt][reg];
      }
  }
  __syncthreads();
  if (t < 64) {
    float ss = redS[0][t] + redS[1][t] + redS[2][t] + redS[3][t];
    float qq = redQ[0][t] + redQ[1][t] + redQ[2][t] + redQ[3][t];
    float mean = ss * (1.f / 256.f);
    float var = qq * (1.f / 256.f) - mean * mean;
    mvM[t] = mean;
    mvI[t] = rsqrtf(var + 1e-5f);
  }
  __syncthreads();
  float gv[4], bev[4];
#pragma unroll
  for (int ct = 0; ct < 4; ct++) { gv[ct] = g[colbase + ct * 16]; bev[ct] = be[colbase + ct * 16]; }
#pragma unroll
  for (int rt = 0; rt < 4; rt++)
#pragma unroll
    for (int reg = 0; reg < 4; reg++) {
      int rr = rt * 16 + kq * 4 + reg;
      int r = row0 + rr;
      if (r >= NN) continue;
      float mean = mvM[rr], inv = mvI[rr];
#pragma unroll
      for (int ct = 0; ct < 4; ct++) {
        int col = colbase + ct * 16;
        float val = fmaxf((acc[rt][ct][reg] - mean) * inv * gv[ct] + bev[ct], 0.f);
        if (EPI == 2) {
          val += resid[(size_t)r * 256 + col];
          outf[(size_t)r * 256 + col] = val;
        }
        outb[(size_t)r * 256 + col] = f2bf(val);
      }
    }
}

// ------------- attention logits: bf16 MFMA, block 64 rows x 128 cols (one head) -------------
__global__ __launch_bounds__(256) void k_att(const unsigned short* __restrict__ hb,
    const unsigned short* __restrict__ W1T, const float* __restrict__ b1,
    const float* __restrict__ W2, const float* __restrict__ b2,
    float* __restrict__ logitsT) {
  __shared__ unsigned short As[64 * 40];
  __shared__ unsigned short Bs[128 * 40];
  __shared__ float redS[4][64];
  int t = threadIdx.x, lane = t & 63, wave = t >> 6;
  int kh = blockIdx.y;
  int row0 = blockIdx.x * 64;
  const unsigned short* Bt = W1T + (size_t)kh * 128 * 256;
  f32x4 acc[4][2];
#pragma unroll
  for (int i = 0; i < 4; i++)
#pragma unroll
    for (int j = 0; j < 2; j++) acc[i][j] = (f32x4)(0.f);
  int arow = t >> 2, ac = t & 3;
  int agr = row0 + arow; if (agr >= NN) agr = NN - 1;
  int m16 = lane & 15, kq = lane >> 4;
  for (int k0 = 0; k0 < 256; k0 += 32) {
    *(float4*)&As[arow * 40 + ac * 8] = *(const float4*)&hb[(size_t)agr * 256 + k0 + ac * 8];
#pragma unroll
    for (int it = 0; it < 2; it++) {
      int idx = t + it * 256;
      int br = idx >> 2, bc = idx & 3;
      *(float4*)&Bs[br * 40 + bc * 8] = *(const float4*)&Bt[(size_t)br * 256 + k0 + bc * 8];
    }
    __syncthreads();
    short8 a[4], b[2];
#pragma unroll
    for (int rt = 0; rt < 4; rt++) a[rt] = *(const short8*)&As[(rt * 16 + m16) * 40 + kq * 8];
#pragma unroll
    for (int ct = 0; ct < 2; ct++)
      b[ct] = *(const short8*)&Bs[(wave * 32 + ct * 16 + m16) * 40 + kq * 8];
#pragma unroll
    for (int rt = 0; rt < 4; rt++)
#pragma unroll
      for (int ct = 0; ct < 2; ct++)
        acc[rt][ct] = __builtin_amdgcn_mfma_f32_16x16x32_bf16(a[rt], b[ct], acc[rt][ct], 0, 0, 0);
    __syncthreads();
  }
  const float* b1k = b1 + kh * 128;
  const float* w2k = W2 + kh * 128;
  float b1v[2], w2v[2];
#pragma unroll
  for (int ct = 0; ct < 2; ct++) {
    int col = wave * 32 + ct * 16 + m16;
    b1v[ct] = b1k[col];
    w2v[ct] = w2k[col];
  }
  float p[4][4];
#pragma unroll
  for (int rt = 0; rt < 4; rt++)
#pragma unroll
    for (int reg = 0; reg < 4; reg++) p[rt][reg] = 0.f;
#pragma unroll
  for (int rt = 0; rt < 4; rt++)
#pragma unroll
    for (int ct = 0; ct < 2; ct++)
#pragma unroll
      for (int reg = 0; reg < 4; reg++)
        p[rt][reg] += tanhf(acc[rt][ct][reg] + b1v[ct]) * w2v[ct];
#pragma unroll
  for (int off = 1; off < 16; off <<= 1)
#pragma unroll
    for (int rt = 0; rt < 4; rt++)
#pragma unroll
      for (int reg = 0; reg < 4; reg++) p[rt][reg] += __shfl_xor(p[rt][reg], off, 64);
  if (m16 == 0) {
#pragma unroll
    for (int rt = 0; rt < 4; rt++)
#pragma unroll
      for (int reg = 0; reg < 4; reg++) redS[wave][rt * 16 + kq * 4 + reg] = p[rt][reg];
  }
  __syncthreads();
  if (t < 64) {
    int r = row0 + t;
    if (r < NN) {
      float sv = redS[0][t] + redS[1][t] + redS[2][t] + redS[3][t] + b2[kh];
      logitsT[(size_t)kh * NN + r] = sv;
    }
  }
}

// ---------------- softmax over N per head ----------------
__global__ void k_smax1(const float* __restrict__ logitsT, float* __restrict__ pmax,
                        float* __restrict__ psum) {
  int k = blockIdx.y;
  int tid = threadIdx.x;
  const float* L = logitsT + (size_t)k * NN;
  __shared__ float sm[256];
  float mx = -1e30f;
  for (int i = blockIdx.x * 256 + tid; i < NN; i += 128 * 256) mx = fmaxf(mx, L[i]);
  sm[tid] = mx; __syncthreads();
  for (int o = 128; o >= 1; o >>= 1) { if (tid < o) sm[tid] = fmaxf(sm[tid], sm[tid + o]); __syncthreads(); }
  float bmax = sm[0];
  __syncthreads();
  float s = 0.f;
  for (int i = blockIdx.x * 256 + tid; i < NN; i += 128 * 256) s += __expf(L[i] - bmax);
  sm[tid] = s; __syncthreads();
  for (int o = 128; o >= 1; o >>= 1) { if (tid < o) sm[tid] += sm[tid + o]; __syncthreads(); }
  if (tid == 0) { pmax[k * 128 + blockIdx.x] = bmax; psum[k * 128 + blockIdx.x] = sm[0]; }
}

__global__ void k_smax2(const float* __restrict__ pmax, const float* __restrict__ psum,
                        float* __restrict__ gs) {
  int k = blockIdx.x;
  int tid = threadIdx.x;  // 128
  __shared__ float sm[128], sv[128];
  float m = pmax[k * 128 + tid];
  sm[tid] = m; __syncthreads();
  for (int o = 64; o >= 1; o >>= 1) { if (tid < o) sm[tid] = fmaxf(sm[tid], sm[tid + o]); __syncthreads(); }
  float gm = sm[0];
  __syncthreads();
  sv[tid] = psum[k * 128 + tid] * __expf(m - gm);
  __syncthreads();
  for (int o = 64; o >= 1; o >>= 1) { if (tid < o) sv[tid] += sv[tid + o]; __syncthreads(); }
  if (tid == 0) { gs[k * 2] = gm; gs[k * 2 + 1] = sv[0]; }
}

// ------------- a = softmax, attn output, z[k][d] partials -------------
__global__ void k_attnz(const float* __restrict__ logitsT, const float* __restrict__ gs,
                        const float* __restrict__ h, float* __restrict__ out_attn,
                        float* __restrict__ z) {
  int n0 = blockIdx.x * 128;
  int tid = threadIdx.x;
  __shared__ float a[4][128];
  for (int i = tid; i < 512; i += 256) {
    int k = i >> 7, n = i & 127;
    float v = 0.f;
    if (n0 + n < NN) v = __expf(logitsT[(size_t)k * NN + n0 + n] - gs[k * 2]) / gs[k * 2 + 1];
    a[k][n] = v;
  }
  __syncthreads();
  for (int i = tid; i < 512; i += 256) {
    int n = i >> 2, k = i & 3;
    if (n0 + n < NN) out_attn[(size_t)(n0 + n) * 4 + k] = a[k][n];
  }
  float z0 = 0.f, z1 = 0.f, z2 = 0.f, z3 = 0.f;
  int d = tid;  // 256 dims
  int nmax = NN - n0; if (nmax > 128) nmax = 128;
  for (int n = 0; n < nmax; n++) {
    float hv = h[(size_t)(n0 + n) * 256 + d];
    z0 += a[0][n] * hv; z1 += a[1][n] * hv; z2 += a[2][n] * hv; z3 += a[3][n] * hv;
  }
  atomicAdd(&z[0 * 256 + d], z0);
  atomicAdd(&z[1 * 256 + d], z1);
  atomicAdd(&z[2 * 256 + d], z2);
  atomicAdd(&z[3 * 256 + d], z3);
}

// ---------------- tiny classifier ----------------
__global__ void k_cls(const float* __restrict__ z, const float* __restrict__ Wc1,
                      const float* __restrict__ bc1, const float* __restrict__ g1,
                      const float* __restrict__ b1, const float* __restrict__ Wc2,
                      const float* __restrict__ bc2, const float* __restrict__ g2,
                      const float* __restrict__ b2, const float* __restrict__ Wc3,
                      const float* __restrict__ bc3, float* __restrict__ out) {
  int tid = threadIdx.x;  // 256
  __shared__ float za[256];
  __shared__ float buf[256];
  __shared__ float c1s[128];
  __shared__ float c2s[64];
  za[tid] = 0.25f * (z[tid] + z[256 + tid] + z[512 + tid] + z[768 + tid]);
  __syncthreads();
  float v1 = 0.f;
  if (tid < 128) {
    for (int d = 0; d < 256; d++) v1 += za[d] * Wc1[d * 128 + tid];
    v1 += bc1[tid];
  }
  buf[tid] = (tid < 128) ? v1 : 0.f; __syncthreads();
  for (int o = 128; o >= 1; o >>= 1) { if (tid < o) buf[tid] += buf[tid + o]; __syncthreads(); }
  float mean1 = buf[0] * (1.f / 128.f);
  __syncthreads();
  buf[tid] = (tid < 128) ? (v1 - mean1) * (v1 - mean1) : 0.f; __syncthreads();
  for (int o = 128; o >= 1; o >>= 1) { if (tid < o) buf[tid] += buf[tid + o]; __syncthreads(); }
  float inv1 = rsqrtf(buf[0] * (1.f / 128.f) + 1e-5f);
  __syncthreads();
  if (tid < 128) c1s[tid] = fmaxf((v1 - mean1) * inv1 * g1[tid] + b1[tid], 0.f);
  __syncthreads();
  float v2 = 0.f;
  if (tid < 64) {
    for (int d = 0; d < 128; d++) v2 += c1s[d] * Wc2[d * 64 + tid];
    v2 += bc2[tid];
  }
  buf[tid] = (tid < 64) ? v2 : 0.f; __syncthreads();
  for (int o = 128; o >= 1; o >>= 1) { if (tid < o) buf[tid] += buf[tid + o]; __syncthreads(); }
  float mean2 = buf[0] * (1.f / 64.f);
  __syncthreads();
  buf[tid] = (tid < 64) ? (v2 - mean2) * (v2 - mean2) : 0.f; __syncthreads();
  for (int o = 128; o >= 1; o >>= 1) { if (tid < o) buf[tid] += buf[tid + o]; __syncthreads(); }
  float inv2 = rsqrtf(buf[0] * (1.f / 64.f) + 1e-5f);
  __syncthreads();
  if (tid < 64) c2s[tid] = fmaxf((v2 - mean2) * inv2 * g2[tid] + b2[tid], 0.f);
  __syncthreads();
  if (tid < 7) {
    float l = 0.f;
    for (int d = 0; d < 64; d++) l += c2s[d] * Wc3[d * 7 + tid];
    buf[tid] = l + bc3[tid];
  }
  __syncthreads();
  if (tid == 0) {
    float mx = -1e30f;
    for (int i = 0; i < 7; i++) mx = fmaxf(mx, buf[i]);
    float s = 0.f;
    for (int i = 0; i < 7; i++) s += __expf(buf[i] - mx);
    for (int i = 0; i < 7; i++) out[i] = __expf(buf[i] - mx) / s;
  }
}

extern "C" void kernel_launch(void* const* d_in, const int* in_sizes, int n_in,
                              void* d_out, int out_size, void* d_ws, size_t ws_size,
                              hipStream_t stream) {
  const float* x       = (const float*)d_in[0];
  const int*   ei      = (const int*)d_in[1];
  const float* W_in    = (const float*)d_in[2];
  const float* b_in    = (const float*)d_in[3];
  const float* gin_W1  = (const float*)d_in[4];
  const float* gin_b1  = (const float*)d_in[5];
  const float* gin_lng = (const float*)d_in[6];
  const float* gin_lnb = (const float*)d_in[7];
  const float* gin_W2  = (const float*)d_in[8];
  const float* gin_b2  = (const float*)d_in[9];
  const float* eps     = (const float*)d_in[10];
  const float* ln_g    = (const float*)d_in[11];
  const float* ln_b    = (const float*)d_in[12];
  const float* att_W1  = (const float*)d_in[13];
  const float* att_b1  = (const float*)d_in[14];
  const float* att_W2  = (const float*)d_in[15];
  const float* att_b2  = (const float*)d_in[16];
  const float* Wc1     = (const float*)d_in[17];
  const float* bc1     = (const float*)d_in[18];
  const float* lnc1_g  = (const float*)d_in[19];
  const float* lnc1_b  = (const float*)d_in[20];
  const float* Wc2     = (const float*)d_in[21];
  const float* bc2     = (const float*)d_in[22];
  const float* lnc2_g  = (const float*)d_in[23];
  const float* lnc2_b  = (const float*)d_in[24];
  const float* Wc3     = (const float*)d_in[25];
  const float* bc3     = (const float*)d_in[26];
  float* out = (float*)d_out;
  (void)in_sizes; (void)n_in; (void)out_size; (void)ws_size;

  char* wsb = (char*)d_ws;
  size_t off = 0;
  auto alloc = [&](size_t bytes) {
    char* p = wsb + off;
    off += (bytes + 255) & ~(size_t)255;
    return p;
  };
  float*          h       = (float*)alloc((size_t)NN * HH * 4);
  unsigned short* hb      = (unsigned short*)alloc((size_t)NN * HH * 2);
  unsigned short* mb1     = (unsigned short*)alloc((size_t)NN * HH * 2);
  unsigned short* mb2     = (unsigned short*)alloc((size_t)NN * HH * 2);
  unsigned short* WinT    = (unsigned short*)alloc((size_t)HH * FF * 2);
  unsigned short* g1T     = (unsigned short*)alloc((size_t)2 * HH * HH * 2);
  unsigned short* g2T     = (unsigned short*)alloc((size_t)2 * HH * HH * 2);
  unsigned short* aW1T    = (unsigned short*)alloc((size_t)4 * 128 * HH * 2);
  float*          logitsT = (float*)alloc((size_t)4 * NN * 4);
  int*            deg     = (int*)alloc((size_t)NN * 4);
  int*            rowptr  = (int*)alloc((size_t)(NN + 1) * 4);
  int*            cursor  = (int*)alloc((size_t)NN * 4);
  int*            csr_src = (int*)alloc((size_t)NE * 4);
  float*          pmax    = (float*)alloc(4 * 128 * 4);
  float*          psum    = (float*)alloc(4 * 128 * 4);
  float*          gs      = (float*)alloc(8 * 4);
  float*          z       = (float*)alloc(4 * 256 * 4);

  const int* srcv = ei;
  const int* dstv = ei + NE;

  // weight transposes + casts (tiny)
  k_tcast<<<dim3((HH + 31) / 32, (FF + 31) / 32), 256, 0, stream>>>(W_in, WinT, FF, HH);
  for (int l = 0; l < 2; l++) {
    k_tcast<<<dim3(8, 8), 256, 0, stream>>>(gin_W1 + (size_t)l * HH * HH, g1T + (size_t)l * HH * HH, HH, HH);
    k_tcast<<<dim3(8, 8), 256, 0, stream>>>(gin_W2 + (size_t)l * HH * HH, g2T + (size_t)l * HH * HH, HH, HH);
  }
  for (int kh = 0; kh < 4; kh++)
    k_tcast<<<dim3(4, 8), 256, 0, stream>>>(att_W1 + (size_t)kh * HH * 128, aW1T + (size_t)kh * 128 * HH, HH, 128);

  // CSR build
  hipMemsetAsync(deg, 0, (size_t)NN * 4, stream);
  hipMemsetAsync(z, 0, 4 * 256 * 4, stream);
  k_count<<<(NE + 255) / 256, 256, 0, stream>>>(dstv, deg);
  k_scan<<<1, 1024, 0, stream>>>(deg, rowptr);
  hipMemcpyAsync(cursor, rowptr, (size_t)NN * 4, hipMemcpyDeviceToDevice, stream);
  k_scatter<<<(NE + 255) / 256, 256, 0, stream>>>(srcv, dstv, cursor, csr_src);

  int gblocks = (NN + 63) / 64;  // 782
  // h = x @ W_in + b_in  (fp32 A cast to bf16 in staging)
  k_mm<FF, 0, true><<<gblocks, 256, 0, stream>>>(x, WinT, b_in, nullptr, nullptr, nullptr, h, nullptr);

  for (int l = 0; l < 2; l++) {
    k_agg<<<(NN + 3) / 4, 256, 0, stream>>>(h, rowptr, csr_src, eps, l, mb1);
    // mb2 = bf16(relu(LN(mb1 @ W1 + b1)))
    k_mm<HH, 1, false><<<gblocks, 256, 0, stream>>>(mb1, g1T + (size_t)l * HH * HH,
        gin_b1 + l * HH, gin_lng + l * HH, gin_lnb + l * HH, nullptr, nullptr, mb2);
    // h = relu(LN(mb2 @ W2 + b2)) + h ; hb = bf16(h)
    k_mm<HH, 2, false><<<gblocks, 256, 0, stream>>>(mb2, g2T + (size_t)l * HH * HH,
        gin_b2 + l * HH, ln_g + l * HH, ln_b + l * HH, h, h, hb);
  }

  k_att<<<dim3(gblocks, 4), 256, 0, stream>>>(hb, aW1T, att_b1, att_W2, att_b2, logitsT);
  k_smax1<<<dim3(128, 4), 256, 0, stream>>>(logitsT, pmax, psum);
  k_smax2<<<4, 128, 0, stream>>>(pmax, psum, gs);
  k_attnz<<<(NN + 127) / 128, 256, 0, stream>>>(logitsT, gs, h, out + 7, z);
  k_cls<<<1, 256, 0, stream>>>(z, Wc1, bc1, lnc1_g, lnc1_b, Wc2, bc2, lnc2_g, lnc2_b,
                               Wc3, bc3, out);
}

// Round 4
// 956.338 us; speedup vs baseline: 1.9489x; 1.0222x over previous
//
#include <hip/hip_runtime.h>
#include <math.h>

#define NN 50000
#define NE 800000
#define FF 768
#define HH 256

typedef __attribute__((ext_vector_type(8))) short short8;
typedef __attribute__((ext_vector_type(4))) float f32x4;

__device__ inline unsigned short f2bf(float f) {
  unsigned u = __float_as_uint(f);
  u = u + 0x7fffu + ((u >> 16) & 1u);
  return (unsigned short)(u >> 16);
}
__device__ inline float bf2f(unsigned short b) {
  return __uint_as_float(((unsigned)b) << 16);
}

// ---------------- CSR build ----------------
__global__ void k_count(const int* __restrict__ dstv, int* __restrict__ deg) {
  int e = blockIdx.x * 256 + threadIdx.x;
  if (e < NE) atomicAdd(&deg[dstv[e]], 1);
}

// single-block thread-coarsened scan: 1024 threads x 49 elems
__global__ void k_scan(const int* __restrict__ deg, int* __restrict__ rowptr) {
  const int CH = 49;  // 1024*49 = 50176 >= NN
  int tid = threadIdx.x;
  int lane = tid & 63, w = tid >> 6;
  int base = tid * CH;
  int sum = 0;
  for (int i = 0; i < CH; i++) {
    int idx = base + i;
    if (idx < NN) sum += deg[idx];
  }
  // inclusive wave scan
  int incl = sum;
  for (int off = 1; off < 64; off <<= 1) {
    int tv = __shfl_up(incl, off, 64);
    if (lane >= off) incl += tv;
  }
  __shared__ int ws[16];
  if (lane == 63) ws[w] = incl;
  __syncthreads();
  if (tid == 0) {
    int c = 0;
    for (int i = 0; i < 16; i++) { int tv = ws[i]; ws[i] = c; c += tv; }
  }
  __syncthreads();
  int run = ws[w] + (incl - sum);  // exclusive prefix for this thread's chunk
  if (tid == 0) rowptr[0] = 0;
  for (int i = 0; i < CH; i++) {
    int idx = base + i;
    if (idx < NN) { run += deg[idx]; rowptr[idx + 1] = run; }
  }
}

__global__ void k_scatter(const int* __restrict__ srcv, const int* __restrict__ dstv,
                          int* __restrict__ cursor, int* __restrict__ csr_src) {
  int e = blockIdx.x * 256 + threadIdx.x;
  if (e < NE) {
    int d = dstv[e];
    int pos = atomicAdd(&cursor[d], 1);
    csr_src[pos] = srcv[e];
  }
}

// ------------- aggregation (bf16 gather): mb = bf16((1+eps)*hb + sum hb[src]) -------------
__global__ void k_agg(const unsigned short* __restrict__ hb, const int* __restrict__ rowptr,
                      const int* __restrict__ csr_src, const float* __restrict__ eps,
                      int layer, unsigned short* __restrict__ mb) {
  int node = (blockIdx.x * blockDim.x + threadIdx.x) >> 6;
  int lane = threadIdx.x & 63;
  if (node >= NN) return;
  int beg = rowptr[node], end = rowptr[node + 1];
  const ushort4* hv = (const ushort4*)hb;
  float ax = 0.f, ay = 0.f, az = 0.f, aw = 0.f;
  for (int e = beg; e < end; ++e) {
    int s = csr_src[e];
    ushort4 v = hv[(size_t)s * 64 + lane];
    ax += bf2f(v.x); ay += bf2f(v.y); az += bf2f(v.z); aw += bf2f(v.w);
  }
  float ep = 1.0f + eps[layer];
  ushort4 h0 = hv[(size_t)node * 64 + lane];
  ax += ep * bf2f(h0.x); ay += ep * bf2f(h0.y);
  az += ep * bf2f(h0.z); aw += ep * bf2f(h0.w);
  ushort4 o;
  o.x = f2bf(ax); o.y = f2bf(ay); o.z = f2bf(az); o.w = f2bf(aw);
  *(ushort4*)&mb[(size_t)node * 256 + lane * 4] = o;
}

// ------------- transpose + cast: dst[c][r] = bf16(src[r][c]), src is R x C -------------
__global__ void k_tcast(const float* __restrict__ src, unsigned short* __restrict__ dst,
                        int R, int C) {
  __shared__ float tile[32][33];
  int bx = blockIdx.x * 32, by = blockIdx.y * 32;
  int tx = threadIdx.x & 31, ty = threadIdx.x >> 5;  // 32 x 8
  for (int i = 0; i < 32; i += 8) {
    int r = by + ty + i, c = bx + tx;
    tile[ty + i][tx] = (r < R && c < C) ? src[(size_t)r * C + c] : 0.f;
  }
  __syncthreads();
  for (int i = 0; i < 32; i += 8) {
    int c = bx + ty + i, r = by + tx;
    if (c < C && r < R) dst[(size_t)c * R + r] = f2bf(tile[tx][ty + i]);
  }
}

// ---------------- bf16 MFMA GEMM: block tile 64 x 256, BK=32 ----------------
// EPI 0: outf = A@B + bias (fp32) and outb = bf16(same)
// EPI 1: outb = bf16(relu(LN(A@B + bias; g,be)))
// EPI 2: v = relu(LN(A@B+bias; g,be)) + resid; outf = v (if WF); outb = bf16(v)
template <int KTOT, int EPI, bool AF32, bool WF>
__global__ __launch_bounds__(256) void k_mm(
    const void* __restrict__ Ap, const unsigned short* __restrict__ Bt,
    const float* __restrict__ bias, const float* __restrict__ g,
    const float* __restrict__ be, const float* __restrict__ resid,
    float* __restrict__ outf, unsigned short* __restrict__ outb) {
  __shared__ unsigned short As[64 * 40];   // 64 rows x 32 k, padded to 40
  __shared__ unsigned short Bs[256 * 40];  // 256 n-rows x 32 k, padded to 40
  __shared__ float redS[4][64];
  __shared__ float redQ[4][64];
  __shared__ float mvM[64], mvI[64];
  int t = threadIdx.x, lane = t & 63, wave = t >> 6;
  int row0 = blockIdx.x * 64;
  f32x4 acc[4][4];
#pragma unroll
  for (int i = 0; i < 4; i++)
#pragma unroll
    for (int j = 0; j < 4; j++) acc[i][j] = (f32x4)(0.f);
  int arow = t >> 2, ac = t & 3;
  int agr = row0 + arow; if (agr >= NN) agr = NN - 1;
  int m16 = lane & 15, kq = lane >> 4;

  for (int k0 = 0; k0 < KTOT; k0 += 32) {
    if (AF32) {
      const float* Af = (const float*)Ap + (size_t)agr * KTOT + k0 + ac * 8;
      float4 f0 = *(const float4*)Af;
      float4 f1 = *(const float4*)(Af + 4);
      short8 v;
      v[0] = (short)f2bf(f0.x); v[1] = (short)f2bf(f0.y);
      v[2] = (short)f2bf(f0.z); v[3] = (short)f2bf(f0.w);
      v[4] = (short)f2bf(f1.x); v[5] = (short)f2bf(f1.y);
      v[6] = (short)f2bf(f1.z); v[7] = (short)f2bf(f1.w);
      *(short8*)&As[arow * 40 + ac * 8] = v;
    } else {
      const unsigned short* Ab = (const unsigned short*)Ap + (size_t)agr * KTOT + k0 + ac * 8;
      *(float4*)&As[arow * 40 + ac * 8] = *(const float4*)Ab;
    }
#pragma unroll
    for (int it = 0; it < 4; it++) {
      int idx = t + it * 256;
      int br = idx >> 2, bc = idx & 3;
      *(float4*)&Bs[br * 40 + bc * 8] = *(const float4*)&Bt[(size_t)br * KTOT + k0 + bc * 8];
    }
    __syncthreads();
    short8 a[4], b[4];
#pragma unroll
    for (int rt = 0; rt < 4; rt++) a[rt] = *(const short8*)&As[(rt * 16 + m16) * 40 + kq * 8];
#pragma unroll
    for (int ct = 0; ct < 4; ct++)
      b[ct] = *(const short8*)&Bs[(wave * 64 + ct * 16 + m16) * 40 + kq * 8];
#pragma unroll
    for (int rt = 0; rt < 4; rt++)
#pragma unroll
      for (int ct = 0; ct < 4; ct++)
        acc[rt][ct] = __builtin_amdgcn_mfma_f32_16x16x32_bf16(a[rt], b[ct], acc[rt][ct], 0, 0, 0);
    __syncthreads();
  }

  int colbase = wave * 64 + m16;
  float bv[4];
#pragma unroll
  for (int ct = 0; ct < 4; ct++) bv[ct] = bias[colbase + ct * 16];

  if (EPI == 0) {
#pragma unroll
    for (int rt = 0; rt < 4; rt++)
#pragma unroll
      for (int reg = 0; reg < 4; reg++) {
        int r = row0 + rt * 16 + kq * 4 + reg;
        if (r < NN) {
#pragma unroll
          for (int ct = 0; ct < 4; ct++) {
            float v = acc[rt][ct][reg] + bv[ct];
            outf[(size_t)r * 256 + colbase + ct * 16] = v;
            outb[(size_t)r * 256 + colbase + ct * 16] = f2bf(v);
          }
        }
      }
    return;
  }

  float s[4][4], q[4][4];
#pragma unroll
  for (int rt = 0; rt < 4; rt++)
#pragma unroll
    for (int reg = 0; reg < 4; reg++) { s[rt][reg] = 0.f; q[rt][reg] = 0.f; }
#pragma unroll
  for (int rt = 0; rt < 4; rt++)
#pragma unroll
    for (int ct = 0; ct < 4; ct++)
#pragma unroll
      for (int reg = 0; reg < 4; reg++) {
        float v = acc[rt][ct][reg] + bv[ct];
        acc[rt][ct][reg] = v;
        s[rt][reg] += v;
        q[rt][reg] += v * v;
      }
#pragma unroll
  for (int off = 1; off < 16; off <<= 1) {
#pragma unroll
    for (int rt = 0; rt < 4; rt++)
#pragma unroll
      for (int reg = 0; reg < 4; reg++) {
        s[rt][reg] += __shfl_xor(s[rt][reg], off, 64);
        q[rt][reg] += __shfl_xor(q[rt][reg], off, 64);
      }
  }
  if (m16 == 0) {
#pragma unroll
    for (int rt = 0; rt < 4; rt++)
#pragma unroll
      for (int reg = 0; reg < 4; reg++) {
        redS[wave][rt * 16 + kq * 4 + reg] = s[rt][reg];
        redQ[wave][rt * 16 + kq * 4 + reg] = q[rt][reg];
      }
  }
  __syncthreads();
  if (t < 64) {
    float ss = redS[0][t] + redS[1][t] + redS[2][t] + redS[3][t];
    float qq = redQ[0][t] + redQ[1][t] + redQ[2][t] + redQ[3][t];
    float mean = ss * (1.f / 256.f);
    float var = qq * (1.f / 256.f) - mean * mean;
    mvM[t] = mean;
    mvI[t] = rsqrtf(var + 1e-5f);
  }
  __syncthreads();
  float gv[4], bev[4];
#pragma unroll
  for (int ct = 0; ct < 4; ct++) { gv[ct] = g[colbase + ct * 16]; bev[ct] = be[colbase + ct * 16]; }
#pragma unroll
  for (int rt = 0; rt < 4; rt++)
#pragma unroll
    for (int reg = 0; reg < 4; reg++) {
      int rr = rt * 16 + kq * 4 + reg;
      int r = row0 + rr;
      if (r >= NN) continue;
      float mean = mvM[rr], inv = mvI[rr];
#pragma unroll
      for (int ct = 0; ct < 4; ct++) {
        int col = colbase + ct * 16;
        float val = fmaxf((acc[rt][ct][reg] - mean) * inv * gv[ct] + bev[ct], 0.f);
        if (EPI == 2) {
          val += resid[(size_t)r * 256 + col];
          if (WF) outf[(size_t)r * 256 + col] = val;
        }
        outb[(size_t)r * 256 + col] = f2bf(val);
      }
    }
}

// ------------- attention logits, 4 heads fused: block 64 rows x (4x128) cols -------------
// wave w computes head w; logits written straight from registers.
__global__ __launch_bounds__(256) void k_att(const unsigned short* __restrict__ hb,
    const unsigned short* __restrict__ W1T, const float* __restrict__ b1,
    const float* __restrict__ W2, const float* __restrict__ b2,
    float* __restrict__ logitsT) {
  __shared__ unsigned short As[64 * 40];
  __shared__ unsigned short Bs[512 * 40];
  int t = threadIdx.x, lane = t & 63, wave = t >> 6;  // wave == head
  int row0 = blockIdx.x * 64;
  f32x4 acc[4][8];
#pragma unroll
  for (int i = 0; i < 4; i++)
#pragma unroll
    for (int j = 0; j < 8; j++) acc[i][j] = (f32x4)(0.f);
  int arow = t >> 2, ac = t & 3;
  int agr = row0 + arow; if (agr >= NN) agr = NN - 1;
  int m16 = lane & 15, kq = lane >> 4;
  for (int k0 = 0; k0 < 256; k0 += 32) {
    *(float4*)&As[arow * 40 + ac * 8] = *(const float4*)&hb[(size_t)agr * 256 + k0 + ac * 8];
#pragma unroll
    for (int it = 0; it < 8; it++) {
      int idx = t + it * 256;
      int br = idx >> 2, bc = idx & 3;
      *(float4*)&Bs[br * 40 + bc * 8] = *(const float4*)&W1T[(size_t)br * 256 + k0 + bc * 8];
    }
    __syncthreads();
    short8 a[4];
#pragma unroll
    for (int rt = 0; rt < 4; rt++) a[rt] = *(const short8*)&As[(rt * 16 + m16) * 40 + kq * 8];
#pragma unroll
    for (int ct = 0; ct < 8; ct++) {
      short8 b = *(const short8*)&Bs[(wave * 128 + ct * 16 + m16) * 40 + kq * 8];
#pragma unroll
      for (int rt = 0; rt < 4; rt++)
        acc[rt][ct] = __builtin_amdgcn_mfma_f32_16x16x32_bf16(a[rt], b, acc[rt][ct], 0, 0, 0);
    }
    __syncthreads();
  }
  const float* b1k = b1 + wave * 128;
  const float* w2k = W2 + wave * 128;
  float p[4][4];
#pragma unroll
  for (int rt = 0; rt < 4; rt++)
#pragma unroll
    for (int reg = 0; reg < 4; reg++) p[rt][reg] = 0.f;
#pragma unroll
  for (int ct = 0; ct < 8; ct++) {
    int col = ct * 16 + m16;
    float b1v = b1k[col], w2v = w2k[col];
#pragma unroll
    for (int rt = 0; rt < 4; rt++)
#pragma unroll
      for (int reg = 0; reg < 4; reg++) {
        float xv = acc[rt][ct][reg] + b1v;
        xv = fminf(fmaxf(xv, -10.f), 10.f);
        float ex = __expf(2.f * xv);
        p[rt][reg] += (ex - 1.f) / (ex + 1.f) * w2v;
      }
  }
#pragma unroll
  for (int off = 1; off < 16; off <<= 1)
#pragma unroll
    for (int rt = 0; rt < 4; rt++)
#pragma unroll
      for (int reg = 0; reg < 4; reg++) p[rt][reg] += __shfl_xor(p[rt][reg], off, 64);
  if (m16 == 0) {
    float b2v = b2[wave];
#pragma unroll
    for (int rt = 0; rt < 4; rt++)
#pragma unroll
      for (int reg = 0; reg < 4; reg++) {
        int r = row0 + rt * 16 + kq * 4 + reg;
        if (r < NN) logitsT[(size_t)wave * NN + r] = p[rt][reg] + b2v;
      }
  }
}

// ---------------- softmax over N per head ----------------
__global__ void k_smax1(const float* __restrict__ logitsT, float* __restrict__ pmax,
                        float* __restrict__ psum) {
  int k = blockIdx.y;
  int tid = threadIdx.x;
  const float* L = logitsT + (size_t)k * NN;
  __shared__ float sm[256];
  float mx = -1e30f;
  for (int i = blockIdx.x * 256 + tid; i < NN; i += 128 * 256) mx = fmaxf(mx, L[i]);
  sm[tid] = mx; __syncthreads();
  for (int o = 128; o >= 1; o >>= 1) { if (tid < o) sm[tid] = fmaxf(sm[tid], sm[tid + o]); __syncthreads(); }
  float bmax = sm[0];
  __syncthreads();
  float s = 0.f;
  for (int i = blockIdx.x * 256 + tid; i < NN; i += 128 * 256) s += __expf(L[i] - bmax);
  sm[tid] = s; __syncthreads();
  for (int o = 128; o >= 1; o >>= 1) { if (tid < o) sm[tid] += sm[tid + o]; __syncthreads(); }
  if (tid == 0) { pmax[k * 128 + blockIdx.x] = bmax; psum[k * 128 + blockIdx.x] = sm[0]; }
}

__global__ void k_smax2(const float* __restrict__ pmax, const float* __restrict__ psum,
                        float* __restrict__ gs) {
  int k = blockIdx.x;
  int tid = threadIdx.x;  // 128
  __shared__ float sm[128], sv[128];
  float m = pmax[k * 128 + tid];
  sm[tid] = m; __syncthreads();
  for (int o = 64; o >= 1; o >>= 1) { if (tid < o) sm[tid] = fmaxf(sm[tid], sm[tid + o]); __syncthreads(); }
  float gm = sm[0];
  __syncthreads();
  sv[tid] = psum[k * 128 + tid] * __expf(m - gm);
  __syncthreads();
  for (int o = 64; o >= 1; o >>= 1) { if (tid < o) sv[tid] += sv[tid + o]; __syncthreads(); }
  if (tid == 0) { gs[k * 2] = gm; gs[k * 2 + 1] = sv[0]; }
}

// ------------- a = softmax, attn output, z[k][d] partials -------------
__global__ void k_attnz(const float* __restrict__ logitsT, const float* __restrict__ gs,
                        const unsigned short* __restrict__ hb, float* __restrict__ out_attn,
                        float* __restrict__ z) {
  int n0 = blockIdx.x * 128;
  int tid = threadIdx.x;
  __shared__ float a[4][128];
  for (int i = tid; i < 512; i += 256) {
    int k = i >> 7, n = i & 127;
    float v = 0.f;
    if (n0 + n < NN) v = __expf(logitsT[(size_t)k * NN + n0 + n] - gs[k * 2]) / gs[k * 2 + 1];
    a[k][n] = v;
  }
  __syncthreads();
  for (int i = tid; i < 512; i += 256) {
    int n = i >> 2, k = i & 3;
    if (n0 + n < NN) out_attn[(size_t)(n0 + n) * 4 + k] = a[k][n];
  }
  float z0 = 0.f, z1 = 0.f, z2 = 0.f, z3 = 0.f;
  int d = tid;  // 256 dims
  int nmax = NN - n0; if (nmax > 128) nmax = 128;
  for (int n = 0; n < nmax; n++) {
    float hv = bf2f(hb[(size_t)(n0 + n) * 256 + d]);
    z0 += a[0][n] * hv; z1 += a[1][n] * hv; z2 += a[2][n] * hv; z3 += a[3][n] * hv;
  }
  atomicAdd(&z[0 * 256 + d], z0);
  atomicAdd(&z[1 * 256 + d], z1);
  atomicAdd(&z[2 * 256 + d], z2);
  atomicAdd(&z[3 * 256 + d], z3);
}

// ---------------- tiny classifier ----------------
__global__ void k_cls(const float* __restrict__ z, const float* __restrict__ Wc1,
                      const float* __restrict__ bc1, const float* __restrict__ g1,
                      const float* __restrict__ b1, const float* __restrict__ Wc2,
                      const float* __restrict__ bc2, const float* __restrict__ g2,
                      const float* __restrict__ b2, const float* __restrict__ Wc3,
                      const float* __restrict__ bc3, float* __restrict__ out) {
  int tid = threadIdx.x;  // 256
  __shared__ float za[256];
  __shared__ float buf[256];
  __shared__ float c1s[128];
  __shared__ float c2s[64];
  za[tid] = 0.25f * (z[tid] + z[256 + tid] + z[512 + tid] + z[768 + tid]);
  __syncthreads();
  float v1 = 0.f;
  if (tid < 128) {
    for (int d = 0; d < 256; d++) v1 += za[d] * Wc1[d * 128 + tid];
    v1 += bc1[tid];
  }
  buf[tid] = (tid < 128) ? v1 : 0.f; __syncthreads();
  for (int o = 128; o >= 1; o >>= 1) { if (tid < o) buf[tid] += buf[tid + o]; __syncthreads(); }
  float mean1 = buf[0] * (1.f / 128.f);
  __syncthreads();
  buf[tid] = (tid < 128) ? (v1 - mean1) * (v1 - mean1) : 0.f; __syncthreads();
  for (int o = 128; o >= 1; o >>= 1) { if (tid < o) buf[tid] += buf[tid + o]; __syncthreads(); }
  float inv1 = rsqrtf(buf[0] * (1.f / 128.f) + 1e-5f);
  __syncthreads();
  if (tid < 128) c1s[tid] = fmaxf((v1 - mean1) * inv1 * g1[tid] + b1[tid], 0.f);
  __syncthreads();
  float v2 = 0.f;
  if (tid < 64) {
    for (int d = 0; d < 128; d++) v2 += c1s[d] * Wc2[d * 64 + tid];
    v2 += bc2[tid];
  }
  buf[tid] = (tid < 64) ? v2 : 0.f; __syncthreads();
  for (int o = 128; o >= 1; o >>= 1) { if (tid < o) buf[tid] += buf[tid + o]; __syncthreads(); }
  float mean2 = buf[0] * (1.f / 64.f);
  __syncthreads();
  buf[tid] = (tid < 64) ? (v2 - mean2) * (v2 - mean2) : 0.f; __syncthreads();
  for (int o = 128; o >= 1; o >>= 1) { if (tid < o) buf[tid] += buf[tid + o]; __syncthreads(); }
  float inv2 = rsqrtf(buf[0] * (1.f / 64.f) + 1e-5f);
  __syncthreads();
  if (tid < 64) c2s[tid] = fmaxf((v2 - mean2) * inv2 * g2[tid] + b2[tid], 0.f);
  __syncthreads();
  if (tid < 7) {
    float l = 0.f;
    for (int d = 0; d < 64; d++) l += c2s[d] * Wc3[d * 7 + tid];
    buf[tid] = l + bc3[tid];
  }
  __syncthreads();
  if (tid == 0) {
    float mx = -1e30f;
    for (int i = 0; i < 7; i++) mx = fmaxf(mx, buf[i]);
    float s = 0.f;
    for (int i = 0; i < 7; i++) s += __expf(buf[i] - mx);
    for (int i = 0; i < 7; i++) out[i] = __expf(buf[i] - mx) / s;
  }
}

extern "C" void kernel_launch(void* const* d_in, const int* in_sizes, int n_in,
                              void* d_out, int out_size, void* d_ws, size_t ws_size,
                              hipStream_t stream) {
  const float* x       = (const float*)d_in[0];
  const int*   ei      = (const int*)d_in[1];
  const float* W_in    = (const float*)d_in[2];
  const float* b_in    = (const float*)d_in[3];
  const float* gin_W1  = (const float*)d_in[4];
  const float* gin_b1  = (const float*)d_in[5];
  const float* gin_lng = (const float*)d_in[6];
  const float* gin_lnb = (const float*)d_in[7];
  const float* gin_W2  = (const float*)d_in[8];
  const float* gin_b2  = (const float*)d_in[9];
  const float* eps     = (const float*)d_in[10];
  const float* ln_g    = (const float*)d_in[11];
  const float* ln_b    = (const float*)d_in[12];
  const float* att_W1  = (const float*)d_in[13];
  const float* att_b1  = (const float*)d_in[14];
  const float* att_W2  = (const float*)d_in[15];
  const float* att_b2  = (const float*)d_in[16];
  const float* Wc1     = (const float*)d_in[17];
  const float* bc1     = (const float*)d_in[18];
  const float* lnc1_g  = (const float*)d_in[19];
  const float* lnc1_b  = (const float*)d_in[20];
  const float* Wc2     = (const float*)d_in[21];
  const float* bc2     = (const float*)d_in[22];
  const float* lnc2_g  = (const float*)d_in[23];
  const float* lnc2_b  = (const float*)d_in[24];
  const float* Wc3     = (const float*)d_in[25];
  const float* bc3     = (const float*)d_in[26];
  float* out = (float*)d_out;
  (void)in_sizes; (void)n_in; (void)out_size; (void)ws_size;

  char* wsb = (char*)d_ws;
  size_t off = 0;
  auto alloc = [&](size_t bytes) {
    char* p = wsb + off;
    off += (bytes + 255) & ~(size_t)255;
    return p;
  };
  float*          h       = (float*)alloc((size_t)NN * HH * 4);
  unsigned short* hb      = (unsigned short*)alloc((size_t)NN * HH * 2);
  unsigned short* mb1     = (unsigned short*)alloc((size_t)NN * HH * 2);
  unsigned short* mb2     = (unsigned short*)alloc((size_t)NN * HH * 2);
  unsigned short* WinT    = (unsigned short*)alloc((size_t)HH * FF * 2);
  unsigned short* g1T     = (unsigned short*)alloc((size_t)2 * HH * HH * 2);
  unsigned short* g2T     = (unsigned short*)alloc((size_t)2 * HH * HH * 2);
  unsigned short* aW1T    = (unsigned short*)alloc((size_t)4 * 128 * HH * 2);
  float*          logitsT = (float*)alloc((size_t)4 * NN * 4);
  int*            deg     = (int*)alloc((size_t)NN * 4);
  int*            rowptr  = (int*)alloc((size_t)(NN + 1) * 4);
  int*            cursor  = (int*)alloc((size_t)NN * 4);
  int*            csr_src = (int*)alloc((size_t)NE * 4);
  float*          pmax    = (float*)alloc(4 * 128 * 4);
  float*          psum    = (float*)alloc(4 * 128 * 4);
  float*          gs      = (float*)alloc(8 * 4);
  float*          z       = (float*)alloc(4 * 256 * 4);

  const int* srcv = ei;
  const int* dstv = ei + NE;

  // weight transposes + casts (tiny)
  k_tcast<<<dim3((HH + 31) / 32, (FF + 31) / 32), 256, 0, stream>>>(W_in, WinT, FF, HH);
  for (int l = 0; l < 2; l++) {
    k_tcast<<<dim3(8, 8), 256, 0, stream>>>(gin_W1 + (size_t)l * HH * HH, g1T + (size_t)l * HH * HH, HH, HH);
    k_tcast<<<dim3(8, 8), 256, 0, stream>>>(gin_W2 + (size_t)l * HH * HH, g2T + (size_t)l * HH * HH, HH, HH);
  }
  for (int kh = 0; kh < 4; kh++)
    k_tcast<<<dim3(4, 8), 256, 0, stream>>>(att_W1 + (size_t)kh * HH * 128, aW1T + (size_t)kh * 128 * HH, HH, 128);

  // CSR build
  hipMemsetAsync(deg, 0, (size_t)NN * 4, stream);
  hipMemsetAsync(z, 0, 4 * 256 * 4, stream);
  k_count<<<(NE + 255) / 256, 256, 0, stream>>>(dstv, deg);
  k_scan<<<1, 1024, 0, stream>>>(deg, rowptr);
  hipMemcpyAsync(cursor, rowptr, (size_t)NN * 4, hipMemcpyDeviceToDevice, stream);
  k_scatter<<<(NE + 255) / 256, 256, 0, stream>>>(srcv, dstv, cursor, csr_src);

  int gblocks = (NN + 63) / 64;  // 782
  // h = x @ W_in + b_in  (fp32 A cast to bf16 in staging); also emit hb
  k_mm<FF, 0, true, true><<<gblocks, 256, 0, stream>>>(x, WinT, b_in, nullptr, nullptr, nullptr, h, hb);

  for (int l = 0; l < 2; l++) {
    k_agg<<<(NN + 3) / 4, 256, 0, stream>>>(hb, rowptr, csr_src, eps, l, mb1);
    // mb2 = bf16(relu(LN(mb1 @ W1 + b1)))
    k_mm<HH, 1, false, true><<<gblocks, 256, 0, stream>>>(mb1, g1T + (size_t)l * HH * HH,
        gin_b1 + l * HH, gin_lng + l * HH, gin_lnb + l * HH, nullptr, nullptr, mb2);
    // h = relu(LN(mb2 @ W2 + b2)) + h ; hb = bf16(h). Last layer: skip fp32 h write.
    if (l == 0)
      k_mm<HH, 2, false, true><<<gblocks, 256, 0, stream>>>(mb2, g2T + (size_t)l * HH * HH,
          gin_b2 + l * HH, ln_g + l * HH, ln_b + l * HH, h, h, hb);
    else
      k_mm<HH, 2, false, false><<<gblocks, 256, 0, stream>>>(mb2, g2T + (size_t)l * HH * HH,
          gin_b2 + l * HH, ln_g + l * HH, ln_b + l * HH, h, nullptr, hb);
  }

  k_att<<<gblocks, 256, 0, stream>>>(hb, aW1T, att_b1, att_W2, att_b2, logitsT);
  k_smax1<<<dim3(128, 4), 256, 0, stream>>>(logitsT, pmax, psum);
  k_smax2<<<4, 128, 0, stream>>>(pmax, psum, gs);
  k_attnz<<<(NN + 127) / 128, 256, 0, stream>>>(logitsT, gs, hb, out + 7, z);
  k_cls<<<1, 256, 0, stream>>>(z, Wc1, bc1, lnc1_g, lnc1_b, Wc2, bc2, lnc2_g, lnc2_b,
                               Wc3, bc3, out);
}